// Round 9
// baseline (243.170 us; speedup 1.0000x reference)
//
#include <hip/hip_runtime.h>
#include <hip/hip_bf16.h>
#include <cmath>

// Problem constants
#define B_ 2
#define NQ_ 900
#define N_ 4096
#define LOG2E 1.4426950408889634f

typedef __attribute__((ext_vector_type(4))) float f32x4;
typedef __attribute__((ext_vector_type(8))) short s16x8;
typedef __attribute__((ext_vector_type(8))) _Float16 f16x8;

__device__ inline short f2bf(float x) {
    union { __hip_bfloat16 b; short s; } u;
    u.b = __float2bfloat16(x);
    return u.s;
}
__device__ inline short f2h(float x) {
    _Float16 h = (_Float16)x;
    return __builtin_bit_cast(short, h);
}

// DPP rotate within 16-lane row (VALU pipe; replaces ds_bpermute shuffles)
template <int CTRL>
__device__ inline float dppf(float x) {
    int xi = __builtin_bit_cast(int, x);
    int r = __builtin_amdgcn_update_dpp(xi, xi, CTRL, 0xF, 0xF, true);
    return __builtin_bit_cast(float, r);
}
__device__ inline float rowmax16(float v) {
    v = fmaxf(v, dppf<0x121>(v));
    v = fmaxf(v, dppf<0x122>(v));
    v = fmaxf(v, dppf<0x124>(v));
    v = fmaxf(v, dppf<0x128>(v));
    return v;
}
__device__ inline float rowsum16(float v) {
    v += dppf<0x121>(v);
    v += dppf<0x122>(v);
    v += dppf<0x124>(v);
    v += dppf<0x128>(v);
    return v;
}

// ---------------------------------------------------------------------------
// Prep: per-launch-constant weight transforms, done ONCE instead of per-block.
//  bx 0..47 : Wq/Wk/Wv -> bf16 W^T[n][k]      (proj B-frags become direct
//             global reads; removes 384 blocks x ~640 inst of W staging)
//  bx 48..63: Wp -> f16 hi/lo W^T pairs        (outproj B path)
//  bx 64    : W2x/W2y * LOG2E -> f16 hi/lo tables in rpe granule order
//             (removes identical staging from 900 rpe3 blocks)
// ---------------------------------------------------------------------------
__global__ __launch_bounds__(256) void prep_kernel(
    const float* __restrict__ Wq, const float* __restrict__ Wk,
    const float* __restrict__ Wv, const float* __restrict__ Wp,
    const float* __restrict__ W2x, const float* __restrict__ W2y,
    unsigned short* __restrict__ wtq, unsigned short* __restrict__ wtk,
    unsigned short* __restrict__ wtv, unsigned short* __restrict__ wph,
    unsigned short* __restrict__ wpl, unsigned short* __restrict__ w2h,
    unsigned short* __restrict__ w2l)
{
    const int bx = blockIdx.x;
    const int tid = threadIdx.x;
    if (bx == 64) {
        for (int i = tid; i < 8192; i += 256) {
            int g = i >> 3, j = i & 7;
            int kcg = g >> 6, rr = g & 63, n = rr >> 2, q4 = rr & 3;
            int k = kcg * 32 + q4 * 8 + j;
            float val = ((n < 8) ? W2x[k * 8 + n] : W2y[k * 8 + (n - 8)]) * LOG2E;
            _Float16 hi = (_Float16)val;
            w2h[i] = (unsigned short)__builtin_bit_cast(short, hi);
            w2l[i] = (unsigned short)f2h(val - (float)hi);
        }
        return;
    }
    const int mtx = bx >> 4, tile = bx & 15;
    const int kt = tile >> 2, ntile = tile & 3;
    const float* W = mtx == 0 ? Wq : mtx == 1 ? Wk : mtx == 2 ? Wv : Wp;
    __shared__ unsigned short th[64][72];
    __shared__ unsigned short tl[64][72];
    #pragma unroll
    for (int p = 0; p < 4; ++p) {
        int kl = p * 16 + (tid >> 4);
        int nl = (tid & 15) * 4;
        float4 v = *(const float4*)(W + (size_t)(kt * 64 + kl) * 256 + ntile * 64 + nl);
        float vv[4] = {v.x, v.y, v.z, v.w};
        #pragma unroll
        for (int i = 0; i < 4; ++i) {
            if (mtx < 3) {
                th[nl + i][kl] = (unsigned short)f2bf(vv[i]);
            } else {
                _Float16 h = (_Float16)vv[i];
                th[nl + i][kl] = (unsigned short)__builtin_bit_cast(short, h);
                tl[nl + i][kl] = (unsigned short)f2h(vv[i] - (float)h);
            }
        }
    }
    __syncthreads();
    unsigned short* dst = mtx == 0 ? wtq : mtx == 1 ? wtk : mtx == 2 ? wtv : wph;
    #pragma unroll
    for (int p = 0; p < 2; ++p) {
        int nl = p * 32 + (tid >> 3);
        int k8 = (tid & 7) * 8;
        uint4 pk;
        unsigned short* ps = (unsigned short*)&pk;
        #pragma unroll
        for (int j = 0; j < 8; ++j) ps[j] = th[nl][k8 + j];
        *(uint4*)(dst + (size_t)(ntile * 64 + nl) * 256 + kt * 64 + k8) = pk;
        if (mtx == 3) {
            #pragma unroll
            for (int j = 0; j < 8; ++j) ps[j] = tl[nl][k8 + j];
            *(uint4*)(wpl + (size_t)(ntile * 64 + nl) * 256 + kt * 64 + k8) = pk;
        }
    }
}

// ---------------------------------------------------------------------------
// Merged Q/K/V projection. B-fragments read DIRECTLY from the prep'd bf16
// W^T (L2-resident, 16 B/lane); Bb LDS + per-n-tile syncs deleted.
// ---------------------------------------------------------------------------
__global__ __launch_bounds__(256) void proj_kernel(
    const float* __restrict__ query, const float* __restrict__ kin,
    const float* __restrict__ vin,
    const unsigned short* __restrict__ wtq, const unsigned short* __restrict__ wtk,
    const unsigned short* __restrict__ wtv,
    const float* __restrict__ bqv, const float* __restrict__ bkv,
    const float* __restrict__ bvv,
    unsigned short* __restrict__ qbf, unsigned short* __restrict__ kbf,
    unsigned short* __restrict__ vbf, float qscale)
{
    const int mtx = blockIdx.z;
    const float* X = mtx == 0 ? query : mtx == 1 ? kin : vin;
    const unsigned short* WT = mtx == 0 ? wtq : mtx == 1 ? wtk : wtv;
    const float* bias = mtx == 0 ? bqv : mtx == 1 ? bkv : bvv;
    unsigned short* Y = mtx == 0 ? qbf : mtx == 1 ? kbf : vbf;
    const int M = mtx == 0 ? 1800 : 8192;
    const int m0 = blockIdx.x * 64;
    if (m0 >= M) return;
    const float alpha = mtx == 0 ? qscale : 1.0f;
    const int rows_per_b = mtx == 0 ? 900 : 4096;
    const int ROWS = mtx == 0 ? 960 : 4096;

    __shared__ short Ab[16384];
    const int tid = threadIdx.x;
    const int w = tid >> 6, l = tid & 63, quad = l >> 4, l15 = l & 15;
    const int wq = tid & 3, mm = tid >> 2;

    {
        const bool valid = (m0 + mm) < M;
        const float* xr = X + (size_t)(m0 + mm) * 256;
        #pragma unroll
        for (int it = 0; it < 8; ++it) {
            int g2 = it * 4 + wq;
            float4 a0 = make_float4(0.f, 0.f, 0.f, 0.f), a1 = a0;
            if (valid) {
                a0 = *(const float4*)(xr + g2 * 8);
                a1 = *(const float4*)(xr + g2 * 8 + 4);
            }
            uint4 pk;
            pk.x = (unsigned)(unsigned short)f2bf(a0.x) | ((unsigned)(unsigned short)f2bf(a0.y) << 16);
            pk.y = (unsigned)(unsigned short)f2bf(a0.z) | ((unsigned)(unsigned short)f2bf(a0.w) << 16);
            pk.z = (unsigned)(unsigned short)f2bf(a1.x) | ((unsigned)(unsigned short)f2bf(a1.y) << 16);
            pk.w = (unsigned)(unsigned short)f2bf(a1.z) | ((unsigned)(unsigned short)f2bf(a1.w) << 16);
            *(uint4*)(Ab + (it * 256 + mm * 4 + wq) * 8) = pk;
        }
    }
    __syncthreads();

    for (int nt0 = 0; nt0 < 4; ++nt0) {
        const int n0 = nt0 * 64;
        f32x4 acc[4] = {{0.f,0.f,0.f,0.f},{0.f,0.f,0.f,0.f},{0.f,0.f,0.f,0.f},{0.f,0.f,0.f,0.f}};
        #pragma unroll
        for (int kc = 0; kc < 8; ++kc) {
            s16x8 a = *(const s16x8*)(Ab + (kc * 256 + (w * 16 + l15) * 4 + quad) * 8);
            #pragma unroll
            for (int nt = 0; nt < 4; ++nt) {
                s16x8 bf = *(const s16x8*)(WT + (size_t)(n0 + nt * 16 + l15) * 256 + kc * 32 + quad * 8);
                acc[nt] = __builtin_amdgcn_mfma_f32_16x16x32_bf16(a, bf, acc[nt], 0, 0, 0);
            }
        }

        #pragma unroll
        for (int nt = 0; nt < 4; ++nt) {
            int n = n0 + nt * 16 + l15;
            float bs = bias[n];
            int h = n >> 5, d = n & 31;
            #pragma unroll
            for (int r = 0; r < 4; ++r) {
                int row = m0 + w * 16 + quad * 4 + r;
                if (row < M) {
                    int b = row / rows_per_b;
                    int pos = row - b * rows_per_b;
                    Y[((size_t)(b * 8 + h) * ROWS + pos) * 32 + d] =
                        (unsigned short)f2bf((acc[nt][r] + bs) * alpha);
                }
            }
        }
    }
}

// ---------------------------------------------------------------------------
// Output projection: B-fragments direct from prep'd f16 hi/lo W^T; only the
// per-iteration X hi/lo split stays in-kernel.
// ---------------------------------------------------------------------------
__global__ __launch_bounds__(256) void outproj_kernel(
    const float* __restrict__ X,
    const unsigned short* __restrict__ wph, const unsigned short* __restrict__ wpl,
    const float* __restrict__ bias, float* __restrict__ Y, int M)
{
    __shared__ short Abh[4096], Abl[4096];
    const int tid = threadIdx.x;
    const int m0 = blockIdx.x * 64, n0 = blockIdx.y * 64;
    const int w = tid >> 6, l = tid & 63, quad = l >> 4, l15 = l & 15;
    const int wq = tid & 3, mm = tid >> 2;
    const bool valid = (m0 + mm) < M;
    const float* xr = X + (size_t)(m0 + mm) * 256;

    f32x4 acc[4] = {{0.f,0.f,0.f,0.f},{0.f,0.f,0.f,0.f},{0.f,0.f,0.f,0.f},{0.f,0.f,0.f,0.f}};

    for (int kq = 0; kq < 4; ++kq) {
        #pragma unroll
        for (int it = 0; it < 2; ++it) {
            int g2 = it * 4 + wq;
            int kbase = kq * 64 + g2 * 8;
            float av[8];
            #pragma unroll
            for (int j = 0; j < 8; ++j)
                av[j] = valid ? xr[kbase + j] : 0.f;
            uint4 ah, al;
            unsigned* ahp = (unsigned*)&ah; unsigned* alp = (unsigned*)&al;
            #pragma unroll
            for (int j2 = 0; j2 < 4; ++j2) {
                _Float16 h0 = (_Float16)av[j2 * 2], h1 = (_Float16)av[j2 * 2 + 1];
                ahp[j2] = (unsigned)(unsigned short)__builtin_bit_cast(short, h0)
                        | ((unsigned)(unsigned short)__builtin_bit_cast(short, h1) << 16);
                alp[j2] = (unsigned)(unsigned short)f2h(av[j2 * 2] - (float)h0)
                        | ((unsigned)(unsigned short)f2h(av[j2 * 2 + 1] - (float)h1) << 16);
            }
            int gi = (it * 256 + mm * 4 + wq) * 8;
            *(uint4*)(Abh + gi) = ah;
            *(uint4*)(Abl + gi) = al;
        }
        __syncthreads();

        #pragma unroll
        for (int kc = 0; kc < 2; ++kc) {
            int ga = (kc * 256 + (w * 16 + l15) * 4 + quad) * 8;
            f16x8 ah = *(const f16x8*)(Abh + ga);
            f16x8 al = *(const f16x8*)(Abl + ga);
            #pragma unroll
            for (int nt = 0; nt < 4; ++nt) {
                size_t gb = (size_t)(n0 + nt * 16 + l15) * 256 + kq * 64 + kc * 32 + quad * 8;
                f16x8 bh = *(const f16x8*)(wph + gb);
                f16x8 bl = *(const f16x8*)(wpl + gb);
                acc[nt] = __builtin_amdgcn_mfma_f32_16x16x32_f16(ah, bh, acc[nt], 0, 0, 0);
                acc[nt] = __builtin_amdgcn_mfma_f32_16x16x32_f16(ah, bl, acc[nt], 0, 0, 0);
                acc[nt] = __builtin_amdgcn_mfma_f32_16x16x32_f16(al, bh, acc[nt], 0, 0, 0);
            }
        }
        __syncthreads();
    }

    #pragma unroll
    for (int nt = 0; nt < 4; ++nt) {
        int n = n0 + nt * 16 + l15;
        float bs = bias[n];
        #pragma unroll
        for (int r = 0; r < 4; ++r) {
            int row = m0 + w * 16 + quad * 4 + r;
            if (row < M)
                Y[(size_t)row * 256 + n] = acc[nt][r] + bs;
        }
    }
}

// ---------------------------------------------------------------------------
// RPE v4: affine-in-pc layer-1; W2 tables read directly from prep'd global
// buffers (1 KB/wave contiguous, L2-hit) — 32 KB LDS + staging deleted.
// ---------------------------------------------------------------------------
__global__ __launch_bounds__(512) void rpe3_kernel(
    const float* __restrict__ ref2d,
    const float* __restrict__ W1x, const float* __restrict__ b1x,
    const float* __restrict__ W1y, const float* __restrict__ b1y,
    const unsigned short* __restrict__ w2h, const unsigned short* __restrict__ w2l,
    float* __restrict__ rpe_x, float* __restrict__ rpe_y)
{
    __shared__ float4 sUV[2 * 576];

    const int tid = threadIdx.x;
    {
        int k = tid;
        float w1x0 = W1x[k], w1x1 = W1x[512 + k];
        float w1y0 = W1y[k], w1y1 = W1y[512 + k];
        float bx = b1x[k], by = b1y[k];
        float vx = -(w1x0 + w1x1), vy = -(w1y0 + w1y1);
        #pragma unroll
        for (int q2 = 0; q2 < 2; ++q2) {
            const float4 bb = *(const float4*)(ref2d + (size_t)(blockIdx.x * 2 + q2) * 4);
            float ux = fmaf(w1x0, bb.x - bb.z * 0.5f, fmaf(w1x1, bb.x + bb.z * 0.5f, bx));
            float uy = fmaf(w1y0, bb.y - bb.w * 0.5f, fmaf(w1y1, bb.y + bb.w * 0.5f, by));
            sUV[q2 * 576 + (k >> 3) * 9 + (k & 7)] = make_float4(ux, vx, uy, vy);
        }
    }

    const int w = tid >> 6, l = tid & 63, quad = l >> 4, l15 = l & 15;
    const int qi = w >> 2, wrow = w & 3;
    const int bq = blockIdx.x * 2 + qi;
    const int row = wrow * 16 + l15;
    const float pc = (row + 0.5f) * 16.0f;

    __syncthreads();

    f32x4 accx = {0.f, 0.f, 0.f, 0.f}, accy = {0.f, 0.f, 0.f, 0.f};
    for (int kc = 0; kc < 16; ++kc) {
        f16x8 axh, axl, ayh, ayl;
        #pragma unroll
        for (int i = 0; i < 8; ++i) {
            float4 u = sUV[qi * 576 + (kc * 4 + quad) * 9 + i];
            float hx = fmaxf(fmaf(u.y, pc, u.x), 0.f);
            float hy = fmaxf(fmaf(u.w, pc, u.z), 0.f);
            _Float16 xh = (_Float16)hx;
            _Float16 yh = (_Float16)hy;
            axh[i] = xh;
            axl[i] = (_Float16)(hx - (float)xh);
            ayh[i] = yh;
            ayl[i] = (_Float16)(hy - (float)yh);
        }
        f16x8 bh = *(const f16x8*)(w2h + (kc * 64 + l15 * 4 + quad) * 8);
        f16x8 bl = *(const f16x8*)(w2l + (kc * 64 + l15 * 4 + quad) * 8);
        accx = __builtin_amdgcn_mfma_f32_16x16x32_f16(axh, bh, accx, 0, 0, 0);
        accx = __builtin_amdgcn_mfma_f32_16x16x32_f16(axh, bl, accx, 0, 0, 0);
        accx = __builtin_amdgcn_mfma_f32_16x16x32_f16(axl, bh, accx, 0, 0, 0);
        accy = __builtin_amdgcn_mfma_f32_16x16x32_f16(ayh, bh, accy, 0, 0, 0);
        accy = __builtin_amdgcn_mfma_f32_16x16x32_f16(ayh, bl, accy, 0, 0, 0);
        accy = __builtin_amdgcn_mfma_f32_16x16x32_f16(ayl, bh, accy, 0, 0, 0);
    }

    #pragma unroll
    for (int rr = 0; rr < 4; ++rr) {
        int row_out = wrow * 16 + quad * 4 + rr;
        if (l15 < 8) rpe_x[((size_t)l15 * 1800 + bq) * 64 + row_out] = accx[rr];
        else         rpe_y[((size_t)(l15 - 8) * 1800 + bq) * 64 + row_out] = accy[rr];
    }
}

// ---------------------------------------------------------------------------
// MFMA flash attention (round-1/8 verified config — unchanged).
// ---------------------------------------------------------------------------
__global__ __launch_bounds__(512, 4) void attn_mfma_kernel(
    const unsigned short* __restrict__ qb16, const unsigned short* __restrict__ kb16,
    const unsigned short* __restrict__ vb16,
    const float* __restrict__ rpe_x, const float* __restrict__ rpe_y,
    const unsigned char* __restrict__ mask, float* __restrict__ xout)
{
    __shared__ short skf[4 * 2048];
    __shared__ short svt[4 * 2048];
    __shared__ short spb[8 * 544];
    __shared__ float ry[32 * 65];
    __shared__ unsigned long long smaskb[64];
    __shared__ float sm[8][16], sl[8][16], sLf[32];

    const int tid = threadIdx.x;
    const int qb = blockIdx.x, h = blockIdx.y, b = blockIdx.z;
    const int q0 = qb * 32;
    const int w = tid >> 6, l = tid & 63;
    const int qsub = w >> 2, g = w & 3;
    const int quad = l >> 4, l15 = l & 15;

    const unsigned short* qg = qb16 + (size_t)(b * 8 + h) * 960 * 32;
    const unsigned short* kg = kb16 + (size_t)(b * 8 + h) * 4096 * 32;
    const unsigned short* vg = vb16 + (size_t)(b * 8 + h) * 4096 * 32;
    const float* rxh = rpe_x + ((size_t)h * 1800 + b * NQ_) * 64;
    const float* ryh = rpe_y + ((size_t)h * 1800 + b * NQ_) * 64;

    for (int i = tid; i < 2048; i += 512) {
        int qq = q0 + (i >> 6), pos = i & 63;
        float vy = 0.f;
        if (qq < NQ_)
            vy = ryh[(size_t)qq * 64 + pos];
        ry[(i >> 6) * 65 + pos] = vy;
    }
    #pragma unroll
    for (int j = 0; j < 8; ++j) {
        int c = w * 8 + j;
        unsigned long long bits = __ballot(mask[(size_t)b * N_ + c * 64 + l] != 0);
        if (l == 0) smaskb[c] = bits;
    }

    s16x8 qa = *(const s16x8*)(qg + (size_t)(q0 + qsub * 16 + l15) * 32 + quad * 8);

    f32x4 rx4[4];
    #pragma unroll
    for (int t = 0; t < 4; ++t)
        #pragma unroll
        for (int r = 0; r < 4; ++r) {
            int qq = q0 + qsub * 16 + quad * 4 + r;
            rx4[t][r] = (qq < NQ_) ? rxh[(size_t)qq * 64 + t * 16 + l15] : 0.f;
        }

    const int sg = tid >> 7, role = (tid >> 6) & 1, stl = tid & 63;
    int eoff[4];
    if (role == 0) {
        #pragma unroll
        for (int t = 0; t < 4; ++t)
            eoff[t] = (t * 16 + (stl & 15)) * 32 + (stl >> 4) * 8;
    } else {
        #pragma unroll
        for (int t = 0; t < 4; ++t)
            eoff[t] = stl * 32 + t * 8;
    }
    const unsigned short* src = role ? vg : kg;

    uint4 pf[4];
    {
        size_t cb = (size_t)(sg * 16) * 2048;
        #pragma unroll
        for (int t = 0; t < 4; ++t) pf[t] = *(const uint4*)(src + cb + eoff[t]);
    }

    float mrow[4] = {-INFINITY, -INFINITY, -INFINITY, -INFINITY};
    float lrow[4] = {0.f, 0.f, 0.f, 0.f};
    f32x4 acc0 = {0.f, 0.f, 0.f, 0.f}, acc1 = {0.f, 0.f, 0.f, 0.f};
    short* pw = spb + w * 544;

    for (int i = 0; i < 16; ++i) {
        __syncthreads();
        if (role == 0) {
            #pragma unroll
            for (int t = 0; t < 4; ++t)
                *(uint4*)(skf + sg * 2048 + (t * 64 + stl) * 8) = pf[t];
        } else {
            short* vtw = svt + sg * 2048;
            #pragma unroll
            for (int t = 0; t < 4; ++t) {
                const unsigned short* pv = (const unsigned short*)&pf[t];
                #pragma unroll
                for (int j = 0; j < 8; ++j) {
                    int d = t * 8 + j;
                    vtw[d * 64 + (((stl >> 3) ^ (d & 7)) << 3) + (stl & 7)] = (short)pv[j];
                }
            }
        }
        __syncthreads();

        {
            int inext = (i + 1 < 16) ? i + 1 : 15;
            size_t cb = (size_t)(sg * 16 + inext) * 2048;
            #pragma unroll
            for (int t = 0; t < 4; ++t) pf[t] = *(const uint4*)(src + cb + eoff[t]);
        }

        const int cgc = g * 16 + i;
        const short* kf = skf + g * 2048;

        f32x4 sc[4];
        #pragma unroll
        for (int t = 0; t < 4; ++t) {
            s16x8 kb = *(const s16x8*)(kf + (t * 64 + l) * 8);
            sc[t] = __builtin_amdgcn_mfma_f32_16x16x32_bf16(qa, kb, rx4[t], 0, 0, 0);
        }
        float ryv[4];
        #pragma unroll
        for (int r = 0; r < 4; ++r)
            ryv[r] = ry[(qsub * 16 + quad * 4 + r) * 65 + cgc];
        unsigned long long mb = smaskb[cgc];
        if (mb) {
            #pragma unroll
            for (int t = 0; t < 4; ++t) {
                float mk = ((mb >> (t * 16 + l15)) & 1ULL) ? -144.2695f : 0.f;
                #pragma unroll
                for (int r = 0; r < 4; ++r) sc[t][r] += mk;
            }
        }

        float cmr[4];
        #pragma unroll
        for (int r = 0; r < 4; ++r)
            cmr[r] = fmaxf(fmaxf(sc[0][r], sc[1][r]), fmaxf(sc[2][r], sc[3][r])) + ryv[r];

        int ok = (cmr[0] <= mrow[0] + 8.f) & (cmr[1] <= mrow[1] + 8.f)
               & (cmr[2] <= mrow[2] + 8.f) & (cmr[3] <= mrow[3] + 8.f);
        if (!__all(ok)) {
            #pragma unroll
            for (int r = 0; r < 4; ++r) {
                float cm = rowmax16(cmr[r]);
                float mnew = fmaxf(mrow[r], cm);
                float al = exp2f(mrow[r] - mnew);
                mrow[r] = mnew;
                lrow[r] *= al;
                acc0[r] *= al;
                acc1[r] *= al;
            }
        }

        float msub[4];
        #pragma unroll
        for (int r = 0; r < 4; ++r) msub[r] = mrow[r] - ryv[r];
        #pragma unroll
        for (int t = 0; t < 4; ++t)
            #pragma unroll
            for (int r = 0; r < 4; ++r)
                sc[t][r] = exp2f(sc[t][r] - msub[r]);
        #pragma unroll
        for (int r = 0; r < 4; ++r)
            lrow[r] += (sc[0][r] + sc[1][r]) + (sc[2][r] + sc[3][r]);

        const short* vt = svt + g * 2048;
        #pragma unroll
        for (int hh = 0; hh < 2; ++hh) {
            #pragma unroll
            for (int tt = 0; tt < 2; ++tt) {
                int t = hh * 2 + tt;
                int gphys = (tt * 2 + (l15 >> 3)) ^ quad;
                #pragma unroll
                for (int r = 0; r < 4; ++r)
                    pw[(gphys * 17 + quad * 4 + r) * 8 + (l15 & 7)] = f2bf(sc[t][r]);
            }
            int gph_r = quad ^ (l15 >> 2);
            s16x8 pa  = *(const s16x8*)(pw + (gph_r * 17 + l15) * 8);
            int ksw = ((hh * 4 + quad) ^ (l15 & 7)) * 8;
            s16x8 vb0 = *(const s16x8*)(vt + l15 * 64 + ksw);
            s16x8 vb1 = *(const s16x8*)(vt + (16 + l15) * 64 + ksw);
            acc0 = __builtin_amdgcn_mfma_f32_16x16x32_bf16(pa, vb0, acc0, 0, 0, 0);
            acc1 = __builtin_amdgcn_mfma_f32_16x16x32_bf16(pa, vb1, acc1, 0, 0, 0);
        }
    }

    #pragma unroll
    for (int r = 0; r < 4; ++r) lrow[r] = rowsum16(lrow[r]);

    __syncthreads();
    if (l15 == 0) {
        #pragma unroll
        for (int r = 0; r < 4; ++r) {
            sm[w][quad * 4 + r] = mrow[r];
            sl[w][quad * 4 + r] = lrow[r];
        }
    }
    __syncthreads();
    float wgt[4], L4[4];
    #pragma unroll
    for (int r = 0; r < 4; ++r) {
        int qrow = quad * 4 + r;
        float mm = -INFINITY;
        #pragma unroll
        for (int gg = 0; gg < 4; ++gg) mm = fmaxf(mm, sm[qsub * 4 + gg][qrow]);
        float LL = 0.f;
        #pragma unroll
        for (int gg = 0; gg < 4; ++gg)
            LL += exp2f(sm[qsub * 4 + gg][qrow] - mm) * sl[qsub * 4 + gg][qrow];
        wgt[r] = exp2f(mrow[r] - mm);
        L4[r] = LL;
    }
    if (g == 0 && l15 == 0) {
        #pragma unroll
        for (int r = 0; r < 4; ++r) sLf[qsub * 16 + quad * 4 + r] = L4[r];
    }

    float* obuf = (float*)skf;
    for (int gg = 0; gg < 4; ++gg) {
        if (g == gg) {
            #pragma unroll
            for (int r = 0; r < 4; ++r) {
                int idx = (qsub * 16 + quad * 4 + r) * 33 + l15;
                float v0 = wgt[r] * acc0[r];
                float v1 = wgt[r] * acc1[r];
                if (gg == 0) { obuf[idx] = v0; obuf[idx + 16] = v1; }
                else         { obuf[idx] += v0; obuf[idx + 16] += v1; }
            }
        }
        __syncthreads();
    }

    for (int i = tid; i < 1024; i += 512) {
        int ql = i >> 5, d = i & 31;
        int qq = q0 + ql;
        if (qq < NQ_)
            xout[(size_t)(b * NQ_ + qq) * 256 + h * 32 + d] = obuf[ql * 33 + d] / sLf[ql];
    }
}

// ---------------------------------------------------------------------------
extern "C" void kernel_launch(void* const* d_in, const int* in_sizes, int n_in,
                              void* d_out, int out_size, void* d_ws, size_t ws_size,
                              hipStream_t stream)
{
    const float* query = (const float*)d_in[1];
    const float* ref2d = (const float*)d_in[2];
    const float* kin   = (const float*)d_in[3];
    const float* vin   = (const float*)d_in[4];
    const unsigned char* mask = (const unsigned char*)d_in[6];
    const float* W1x = (const float*)d_in[7];
    const float* b1x = (const float*)d_in[8];
    const float* W2x = (const float*)d_in[9];
    const float* W1y = (const float*)d_in[10];
    const float* b1y = (const float*)d_in[11];
    const float* W2y = (const float*)d_in[12];
    const float* Wq  = (const float*)d_in[13];
    const float* bq  = (const float*)d_in[14];
    const float* Wk  = (const float*)d_in[15];
    const float* bk  = (const float*)d_in[16];
    const float* Wv  = (const float*)d_in[17];
    const float* bv  = (const float*)d_in[18];
    const float* Wp  = (const float*)d_in[19];
    const float* bp  = (const float*)d_in[20];

    // Workspace ~19.3 MB (proven-safe footprint 27.8 MB)
    char* wsb = (char*)d_ws;
    unsigned short* qbf = (unsigned short*)(wsb);               //   983040 B
    unsigned short* kbf = (unsigned short*)(wsb +   983040);    //  4194304 B
    unsigned short* vbf = (unsigned short*)(wsb +  5177344);    //  4194304 B
    float* rxws = (float*)(wsb +  9371648);                     //  3686400 B
    float* ryws = (float*)(wsb + 13058048);                     //  3686400 B
    float* xws  = (float*)(wsb + 16744448);                     //  1843200 B
    unsigned short* wtq = (unsigned short*)(wsb + 18587648);    //   131072 B
    unsigned short* wtk = (unsigned short*)(wsb + 18718720);    //   131072 B
    unsigned short* wtv = (unsigned short*)(wsb + 18849792);    //   131072 B
    unsigned short* wph = (unsigned short*)(wsb + 18980864);    //   131072 B
    unsigned short* wpl = (unsigned short*)(wsb + 19111936);    //   131072 B
    unsigned short* w2h = (unsigned short*)(wsb + 19243008);    //    16384 B
    unsigned short* w2l = (unsigned short*)(wsb + 19259392);    //    16384 B
    float* out  = (float*)d_out;

    const float qscale = LOG2E / sqrtf(32.0f);   // exp2-domain softmax

    prep_kernel<<<65, 256, 0, stream>>>(
        Wq, Wk, Wv, Wp, W2x, W2y, wtq, wtk, wtv, wph, wpl, w2h, w2l);
    proj_kernel<<<dim3(128, 1, 3), 256, 0, stream>>>(
        query, kin, vin, wtq, wtk, wtv, bq, bk, bv, qbf, kbf, vbf, qscale);
    rpe3_kernel<<<900, 512, 0, stream>>>(
        ref2d, W1x, b1x, W1y, b1y, w2h, w2l, rxws, ryws);
    attn_mfma_kernel<<<dim3(29, 8, B_), 512, 0, stream>>>(
        qbf, kbf, vbf, rxws, ryws, mask, xws);
    outproj_kernel<<<dim3(29, 4), 256, 0, stream>>>(xws, wph, wpl, bp, out, 1800);
}

// Round 10
// 217.966 us; speedup vs baseline: 1.1156x; 1.1156x over previous
//
#include <hip/hip_runtime.h>
#include <hip/hip_bf16.h>
#include <cmath>

// Problem constants
#define B_ 2
#define NQ_ 900
#define N_ 4096
#define LOG2E 1.4426950408889634f

typedef __attribute__((ext_vector_type(4))) float f32x4;
typedef __attribute__((ext_vector_type(8))) short s16x8;
typedef __attribute__((ext_vector_type(8))) _Float16 f16x8;

__device__ inline short f2bf(float x) {
    union { __hip_bfloat16 b; short s; } u;
    u.b = __float2bfloat16(x);
    return u.s;
}
__device__ inline short f2h(float x) {
    _Float16 h = (_Float16)x;
    return __builtin_bit_cast(short, h);
}

// DPP rotate within 16-lane row (VALU pipe; replaces ds_bpermute shuffles)
template <int CTRL>
__device__ inline float dppf(float x) {
    int xi = __builtin_bit_cast(int, x);
    int r = __builtin_amdgcn_update_dpp(xi, xi, CTRL, 0xF, 0xF, true);
    return __builtin_bit_cast(float, r);
}
__device__ inline float rowmax16(float v) {
    v = fmaxf(v, dppf<0x121>(v));
    v = fmaxf(v, dppf<0x122>(v));
    v = fmaxf(v, dppf<0x124>(v));
    v = fmaxf(v, dppf<0x128>(v));
    return v;
}
__device__ inline float rowsum16(float v) {
    v += dppf<0x121>(v);
    v += dppf<0x122>(v);
    v += dppf<0x124>(v);
    v += dppf<0x128>(v);
    return v;
}

// ---------------------------------------------------------------------------
// Stage 1 (FUSED): proj + rpe3 in one launch. They are data-independent;
// fusing saves one ~10us launch (round-9 measured prep launch cost) and
// overlaps proj's HBM/MFMA phase with rpe3's VALU-latency phase.
//  blocks 0..284   : Q/K/V projection (mtx decoded; Bb staged in two K=128
//                    halves so LDS = 32+16 = 48 KB -> 3 blocks/CU)
//  blocks 285..2084: rpe3, 1 query per 256-thread block (sUV 9.2 KB;
//                    sw2 tables 32 KB; union fits 48 KB)
// ---------------------------------------------------------------------------
__global__ __launch_bounds__(256) void stage1_kernel(
    const float* __restrict__ query, const float* __restrict__ kin,
    const float* __restrict__ vin,
    const float* __restrict__ Wq, const float* __restrict__ Wk,
    const float* __restrict__ Wv,
    const float* __restrict__ bqv, const float* __restrict__ bkv,
    const float* __restrict__ bvv,
    unsigned short* __restrict__ qbf, unsigned short* __restrict__ kbf,
    unsigned short* __restrict__ vbf, float qscale,
    const float* __restrict__ ref2d,
    const float* __restrict__ W1x, const float* __restrict__ b1x,
    const float* __restrict__ W1y, const float* __restrict__ b1y,
    const float* __restrict__ W2x, const float* __restrict__ W2y,
    float* __restrict__ rpe_x, float* __restrict__ rpe_y)
{
    __shared__ uint4 smem[3072];          // 48 KB union
    const int bx = blockIdx.x;
    const int tid = threadIdx.x;
    const int w = tid >> 6, l = tid & 63, quad = l >> 4, l15 = l & 15;

    if (bx < 285) {
        // ------------------------------ proj ------------------------------
        short* Ab = (short*)smem;                    // 32 KB
        short* Bb = (short*)smem + 16384;            // 16 KB (one K-half)
        const int mtx = bx < 29 ? 0 : (bx < 157 ? 1 : 2);
        const int tile = bx - (mtx == 0 ? 0 : mtx == 1 ? 29 : 157);
        const int m0 = tile * 64;
        const float* X = mtx == 0 ? query : mtx == 1 ? kin : vin;
        const float* W = mtx == 0 ? Wq : mtx == 1 ? Wk : Wv;
        const float* bias = mtx == 0 ? bqv : mtx == 1 ? bkv : bvv;
        unsigned short* Y = mtx == 0 ? qbf : mtx == 1 ? kbf : vbf;
        const int M = mtx == 0 ? 1800 : 8192;
        const float alpha = mtx == 0 ? qscale : 1.0f;
        const int rows_per_b = mtx == 0 ? 900 : 4096;
        const int ROWS = mtx == 0 ? 960 : 4096;
        const int wq = tid & 3, mm = tid >> 2;

        {
            const bool valid = (m0 + mm) < M;
            const float* xr = X + (size_t)(m0 + mm) * 256;
            #pragma unroll
            for (int it = 0; it < 8; ++it) {
                int g2 = it * 4 + wq;
                float4 a0 = make_float4(0.f, 0.f, 0.f, 0.f), a1 = a0;
                if (valid) {
                    a0 = *(const float4*)(xr + g2 * 8);
                    a1 = *(const float4*)(xr + g2 * 8 + 4);
                }
                uint4 pk;
                pk.x = (unsigned)(unsigned short)f2bf(a0.x) | ((unsigned)(unsigned short)f2bf(a0.y) << 16);
                pk.y = (unsigned)(unsigned short)f2bf(a0.z) | ((unsigned)(unsigned short)f2bf(a0.w) << 16);
                pk.z = (unsigned)(unsigned short)f2bf(a1.x) | ((unsigned)(unsigned short)f2bf(a1.y) << 16);
                pk.w = (unsigned)(unsigned short)f2bf(a1.z) | ((unsigned)(unsigned short)f2bf(a1.w) << 16);
                *(uint4*)(Ab + (it * 256 + mm * 4 + wq) * 8) = pk;
            }
        }

        for (int nt0 = 0; nt0 < 4; ++nt0) {
            const int n0 = nt0 * 64;
            f32x4 acc[4] = {{0.f,0.f,0.f,0.f},{0.f,0.f,0.f,0.f},{0.f,0.f,0.f,0.f},{0.f,0.f,0.f,0.f}};
            for (int kh = 0; kh < 2; ++kh) {
                {
                    const float* wcol = W + n0 + mm;
                    #pragma unroll
                    for (int it = 0; it < 4; ++it) {
                        int g2 = it * 4 + wq;
                        int kb = kh * 128 + g2 * 8;
                        uint4 wk4;
                        wk4.x = (unsigned)(unsigned short)f2bf(wcol[(kb + 0) * 256])
                              | ((unsigned)(unsigned short)f2bf(wcol[(kb + 1) * 256]) << 16);
                        wk4.y = (unsigned)(unsigned short)f2bf(wcol[(kb + 2) * 256])
                              | ((unsigned)(unsigned short)f2bf(wcol[(kb + 3) * 256]) << 16);
                        wk4.z = (unsigned)(unsigned short)f2bf(wcol[(kb + 4) * 256])
                              | ((unsigned)(unsigned short)f2bf(wcol[(kb + 5) * 256]) << 16);
                        wk4.w = (unsigned)(unsigned short)f2bf(wcol[(kb + 6) * 256])
                              | ((unsigned)(unsigned short)f2bf(wcol[(kb + 7) * 256]) << 16);
                        *(uint4*)(Bb + (it * 256 + mm * 4 + wq) * 8) = wk4;
                    }
                }
                __syncthreads();

                #pragma unroll
                for (int kc = 0; kc < 4; ++kc) {
                    int kcg = kh * 4 + kc;
                    s16x8 a = *(const s16x8*)(Ab + (kcg * 256 + (w * 16 + l15) * 4 + quad) * 8);
                    #pragma unroll
                    for (int nt = 0; nt < 4; ++nt) {
                        s16x8 bf = *(const s16x8*)(Bb + (kc * 256 + (nt * 16 + l15) * 4 + quad) * 8);
                        acc[nt] = __builtin_amdgcn_mfma_f32_16x16x32_bf16(a, bf, acc[nt], 0, 0, 0);
                    }
                }
                __syncthreads();
            }

            #pragma unroll
            for (int nt = 0; nt < 4; ++nt) {
                int n = n0 + nt * 16 + l15;
                float bs = bias[n];
                int h = n >> 5, d = n & 31;
                #pragma unroll
                for (int r = 0; r < 4; ++r) {
                    int row = m0 + w * 16 + quad * 4 + r;
                    if (row < M) {
                        int b = row / rows_per_b;
                        int pos = row - b * rows_per_b;
                        Y[((size_t)(b * 8 + h) * ROWS + pos) * 32 + d] =
                            (unsigned short)f2bf((acc[nt][r] + bs) * alpha);
                    }
                }
            }
        }
    } else {
        // ------------------------------ rpe3 ------------------------------
        short* sw2h = (short*)smem;                  // 16 KB
        short* sw2l = (short*)smem + 8192;           // 16 KB
        float4* sUV = (float4*)(smem + 2048);        // 9.2 KB (576 entries)
        const int bq = bx - 285;                     // 0..1799

        for (int i = tid; i < 8192; i += 256) {
            int g = i >> 3, j = i & 7;
            int kcg = g >> 6, rr = g & 63, n = rr >> 2, q4 = rr & 3;
            int k = kcg * 32 + q4 * 8 + j;
            float val = ((n < 8) ? W2x[k * 8 + n] : W2y[k * 8 + (n - 8)]) * LOG2E;
            _Float16 hi = (_Float16)val;
            sw2h[i] = __builtin_bit_cast(short, hi);
            sw2l[i] = f2h(val - (float)hi);
        }
        for (int k = tid; k < 512; k += 256) {
            float w1x0 = W1x[k], w1x1 = W1x[512 + k];
            float w1y0 = W1y[k], w1y1 = W1y[512 + k];
            float bxv = b1x[k], byv = b1y[k];
            float vx = -(w1x0 + w1x1), vy = -(w1y0 + w1y1);
            const float4 bb = *(const float4*)(ref2d + (size_t)bq * 4);
            float ux = fmaf(w1x0, bb.x - bb.z * 0.5f, fmaf(w1x1, bb.x + bb.z * 0.5f, bxv));
            float uy = fmaf(w1y0, bb.y - bb.w * 0.5f, fmaf(w1y1, bb.y + bb.w * 0.5f, byv));
            sUV[(k >> 3) * 9 + (k & 7)] = make_float4(ux, vx, uy, vy);
        }

        const int wrow = w;
        const int row = wrow * 16 + l15;
        const float pc = (row + 0.5f) * 16.0f;

        __syncthreads();

        f32x4 accx = {0.f, 0.f, 0.f, 0.f}, accy = {0.f, 0.f, 0.f, 0.f};
        for (int kc = 0; kc < 16; ++kc) {
            f16x8 axh, axl, ayh, ayl;
            #pragma unroll
            for (int i = 0; i < 8; ++i) {
                float4 u = sUV[(kc * 4 + quad) * 9 + i];
                float hx = fmaxf(fmaf(u.y, pc, u.x), 0.f);
                float hy = fmaxf(fmaf(u.w, pc, u.z), 0.f);
                _Float16 xh = (_Float16)hx;
                _Float16 yh = (_Float16)hy;
                axh[i] = xh;
                axl[i] = (_Float16)(hx - (float)xh);
                ayh[i] = yh;
                ayl[i] = (_Float16)(hy - (float)yh);
            }
            f16x8 bh = *(const f16x8*)(sw2h + (kc * 64 + l15 * 4 + quad) * 8);
            f16x8 bl = *(const f16x8*)(sw2l + (kc * 64 + l15 * 4 + quad) * 8);
            accx = __builtin_amdgcn_mfma_f32_16x16x32_f16(axh, bh, accx, 0, 0, 0);
            accx = __builtin_amdgcn_mfma_f32_16x16x32_f16(axh, bl, accx, 0, 0, 0);
            accx = __builtin_amdgcn_mfma_f32_16x16x32_f16(axl, bh, accx, 0, 0, 0);
            accy = __builtin_amdgcn_mfma_f32_16x16x32_f16(ayh, bh, accy, 0, 0, 0);
            accy = __builtin_amdgcn_mfma_f32_16x16x32_f16(ayh, bl, accy, 0, 0, 0);
            accy = __builtin_amdgcn_mfma_f32_16x16x32_f16(ayl, bh, accy, 0, 0, 0);
        }

        #pragma unroll
        for (int rr = 0; rr < 4; ++rr) {
            int row_out = wrow * 16 + quad * 4 + rr;
            if (l15 < 8) rpe_x[((size_t)l15 * 1800 + bq) * 64 + row_out] = accx[rr];
            else         rpe_y[((size_t)(l15 - 8) * 1800 + bq) * 64 + row_out] = accy[rr];
        }
    }
}

// ---------------------------------------------------------------------------
// Output projection via fp16 hi/lo split MFMA (round-8 verified version).
// ---------------------------------------------------------------------------
__global__ __launch_bounds__(256) void outproj_kernel(
    const float* __restrict__ X, const float* __restrict__ W,
    const float* __restrict__ bias, float* __restrict__ Y, int M)
{
    __shared__ short Abh[4096], Abl[4096], Bbh[4096], Bbl[4096];
    const int tid = threadIdx.x;
    const int m0 = blockIdx.x * 64, n0 = blockIdx.y * 64;
    const int w = tid >> 6, l = tid & 63, quad = l >> 4, l15 = l & 15;
    const int wq = tid & 3, mm = tid >> 2;
    const bool valid = (m0 + mm) < M;
    const float* xr = X + (size_t)(m0 + mm) * 256;
    const float* wcol = W + n0 + mm;

    f32x4 acc[4] = {{0.f,0.f,0.f,0.f},{0.f,0.f,0.f,0.f},{0.f,0.f,0.f,0.f},{0.f,0.f,0.f,0.f}};

    for (int kq = 0; kq < 4; ++kq) {
        #pragma unroll
        for (int it = 0; it < 2; ++it) {
            int g2 = it * 4 + wq;
            int kbase = kq * 64 + g2 * 8;
            float av[8], bv[8];
            #pragma unroll
            for (int j = 0; j < 8; ++j) {
                av[j] = valid ? xr[kbase + j] : 0.f;
                bv[j] = wcol[(kbase + j) * 256];
            }
            uint4 ah, al, bh, bl;
            unsigned* ahp = (unsigned*)&ah; unsigned* alp = (unsigned*)&al;
            unsigned* bhp = (unsigned*)&bh; unsigned* blp = (unsigned*)&bl;
            #pragma unroll
            for (int j2 = 0; j2 < 4; ++j2) {
                _Float16 h0 = (_Float16)av[j2 * 2], h1 = (_Float16)av[j2 * 2 + 1];
                ahp[j2] = (unsigned)(unsigned short)__builtin_bit_cast(short, h0)
                        | ((unsigned)(unsigned short)__builtin_bit_cast(short, h1) << 16);
                alp[j2] = (unsigned)(unsigned short)f2h(av[j2 * 2] - (float)h0)
                        | ((unsigned)(unsigned short)f2h(av[j2 * 2 + 1] - (float)h1) << 16);
                _Float16 g0 = (_Float16)bv[j2 * 2], g1 = (_Float16)bv[j2 * 2 + 1];
                bhp[j2] = (unsigned)(unsigned short)__builtin_bit_cast(short, g0)
                        | ((unsigned)(unsigned short)__builtin_bit_cast(short, g1) << 16);
                blp[j2] = (unsigned)(unsigned short)f2h(bv[j2 * 2] - (float)g0)
                        | ((unsigned)(unsigned short)f2h(bv[j2 * 2 + 1] - (float)g1) << 16);
            }
            int gi = (it * 256 + mm * 4 + wq) * 8;
            *(uint4*)(Abh + gi) = ah;
            *(uint4*)(Abl + gi) = al;
            *(uint4*)(Bbh + gi) = bh;
            *(uint4*)(Bbl + gi) = bl;
        }
        __syncthreads();

        #pragma unroll
        for (int kc = 0; kc < 2; ++kc) {
            int ga = (kc * 256 + (w * 16 + l15) * 4 + quad) * 8;
            f16x8 ah = *(const f16x8*)(Abh + ga);
            f16x8 al = *(const f16x8*)(Abl + ga);
            #pragma unroll
            for (int nt = 0; nt < 4; ++nt) {
                int gb = (kc * 256 + (nt * 16 + l15) * 4 + quad) * 8;
                f16x8 bh = *(const f16x8*)(Bbh + gb);
                f16x8 bl = *(const f16x8*)(Bbl + gb);
                acc[nt] = __builtin_amdgcn_mfma_f32_16x16x32_f16(ah, bh, acc[nt], 0, 0, 0);
                acc[nt] = __builtin_amdgcn_mfma_f32_16x16x32_f16(ah, bl, acc[nt], 0, 0, 0);
                acc[nt] = __builtin_amdgcn_mfma_f32_16x16x32_f16(al, bh, acc[nt], 0, 0, 0);
            }
        }
        __syncthreads();
    }

    #pragma unroll
    for (int nt = 0; nt < 4; ++nt) {
        int n = n0 + nt * 16 + l15;
        float bs = bias[n];
        #pragma unroll
        for (int r = 0; r < 4; ++r) {
            int row = m0 + w * 16 + quad * 4 + r;
            if (row < M)
                Y[(size_t)row * 256 + n] = acc[nt][r] + bs;
        }
    }
}

// ---------------------------------------------------------------------------
// MFMA flash attention (round-1/8 verified config — unchanged).
// ---------------------------------------------------------------------------
__global__ __launch_bounds__(512, 4) void attn_mfma_kernel(
    const unsigned short* __restrict__ qb16, const unsigned short* __restrict__ kb16,
    const unsigned short* __restrict__ vb16,
    const float* __restrict__ rpe_x, const float* __restrict__ rpe_y,
    const unsigned char* __restrict__ mask, float* __restrict__ xout)
{
    __shared__ short skf[4 * 2048];
    __shared__ short svt[4 * 2048];
    __shared__ short spb[8 * 544];
    __shared__ float ry[32 * 65];
    __shared__ unsigned long long smaskb[64];
    __shared__ float sm[8][16], sl[8][16], sLf[32];

    const int tid = threadIdx.x;
    const int qb = blockIdx.x, h = blockIdx.y, b = blockIdx.z;
    const int q0 = qb * 32;
    const int w = tid >> 6, l = tid & 63;
    const int qsub = w >> 2, g = w & 3;
    const int quad = l >> 4, l15 = l & 15;

    const unsigned short* qg = qb16 + (size_t)(b * 8 + h) * 960 * 32;
    const unsigned short* kg = kb16 + (size_t)(b * 8 + h) * 4096 * 32;
    const unsigned short* vg = vb16 + (size_t)(b * 8 + h) * 4096 * 32;
    const float* rxh = rpe_x + ((size_t)h * 1800 + b * NQ_) * 64;
    const float* ryh = rpe_y + ((size_t)h * 1800 + b * NQ_) * 64;

    for (int i = tid; i < 2048; i += 512) {
        int qq = q0 + (i >> 6), pos = i & 63;
        float vy = 0.f;
        if (qq < NQ_)
            vy = ryh[(size_t)qq * 64 + pos];
        ry[(i >> 6) * 65 + pos] = vy;
    }
    #pragma unroll
    for (int j = 0; j < 8; ++j) {
        int c = w * 8 + j;
        unsigned long long bits = __ballot(mask[(size_t)b * N_ + c * 64 + l] != 0);
        if (l == 0) smaskb[c] = bits;
    }

    s16x8 qa = *(const s16x8*)(qg + (size_t)(q0 + qsub * 16 + l15) * 32 + quad * 8);

    f32x4 rx4[4];
    #pragma unroll
    for (int t = 0; t < 4; ++t)
        #pragma unroll
        for (int r = 0; r < 4; ++r) {
            int qq = q0 + qsub * 16 + quad * 4 + r;
            rx4[t][r] = (qq < NQ_) ? rxh[(size_t)qq * 64 + t * 16 + l15] : 0.f;
        }

    const int sg = tid >> 7, role = (tid >> 6) & 1, stl = tid & 63;
    int eoff[4];
    if (role == 0) {
        #pragma unroll
        for (int t = 0; t < 4; ++t)
            eoff[t] = (t * 16 + (stl & 15)) * 32 + (stl >> 4) * 8;
    } else {
        #pragma unroll
        for (int t = 0; t < 4; ++t)
            eoff[t] = stl * 32 + t * 8;
    }
    const unsigned short* src = role ? vg : kg;

    uint4 pf[4];
    {
        size_t cb = (size_t)(sg * 16) * 2048;
        #pragma unroll
        for (int t = 0; t < 4; ++t) pf[t] = *(const uint4*)(src + cb + eoff[t]);
    }

    float mrow[4] = {-INFINITY, -INFINITY, -INFINITY, -INFINITY};
    float lrow[4] = {0.f, 0.f, 0.f, 0.f};
    f32x4 acc0 = {0.f, 0.f, 0.f, 0.f}, acc1 = {0.f, 0.f, 0.f, 0.f};
    short* pw = spb + w * 544;

    for (int i = 0; i < 16; ++i) {
        __syncthreads();
        if (role == 0) {
            #pragma unroll
            for (int t = 0; t < 4; ++t)
                *(uint4*)(skf + sg * 2048 + (t * 64 + stl) * 8) = pf[t];
        } else {
            short* vtw = svt + sg * 2048;
            #pragma unroll
            for (int t = 0; t < 4; ++t) {
                const unsigned short* pv = (const unsigned short*)&pf[t];
                #pragma unroll
                for (int j = 0; j < 8; ++j) {
                    int d = t * 8 + j;
                    vtw[d * 64 + (((stl >> 3) ^ (d & 7)) << 3) + (stl & 7)] = (short)pv[j];
                }
            }
        }
        __syncthreads();

        {
            int inext = (i + 1 < 16) ? i + 1 : 15;
            size_t cb = (size_t)(sg * 16 + inext) * 2048;
            #pragma unroll
            for (int t = 0; t < 4; ++t) pf[t] = *(const uint4*)(src + cb + eoff[t]);
        }

        const int cgc = g * 16 + i;
        const short* kf = skf + g * 2048;

        f32x4 sc[4];
        #pragma unroll
        for (int t = 0; t < 4; ++t) {
            s16x8 kb = *(const s16x8*)(kf + (t * 64 + l) * 8);
            sc[t] = __builtin_amdgcn_mfma_f32_16x16x32_bf16(qa, kb, rx4[t], 0, 0, 0);
        }
        float ryv[4];
        #pragma unroll
        for (int r = 0; r < 4; ++r)
            ryv[r] = ry[(qsub * 16 + quad * 4 + r) * 65 + cgc];
        unsigned long long mb = smaskb[cgc];
        if (mb) {
            #pragma unroll
            for (int t = 0; t < 4; ++t) {
                float mk = ((mb >> (t * 16 + l15)) & 1ULL) ? -144.2695f : 0.f;
                #pragma unroll
                for (int r = 0; r < 4; ++r) sc[t][r] += mk;
            }
        }

        float cmr[4];
        #pragma unroll
        for (int r = 0; r < 4; ++r)
            cmr[r] = fmaxf(fmaxf(sc[0][r], sc[1][r]), fmaxf(sc[2][r], sc[3][r])) + ryv[r];

        int ok = (cmr[0] <= mrow[0] + 8.f) & (cmr[1] <= mrow[1] + 8.f)
               & (cmr[2] <= mrow[2] + 8.f) & (cmr[3] <= mrow[3] + 8.f);
        if (!__all(ok)) {
            #pragma unroll
            for (int r = 0; r < 4; ++r) {
                float cm = rowmax16(cmr[r]);
                float mnew = fmaxf(mrow[r], cm);
                float al = exp2f(mrow[r] - mnew);
                mrow[r] = mnew;
                lrow[r] *= al;
                acc0[r] *= al;
                acc1[r] *= al;
            }
        }

        float msub[4];
        #pragma unroll
        for (int r = 0; r < 4; ++r) msub[r] = mrow[r] - ryv[r];
        #pragma unroll
        for (int t = 0; t < 4; ++t)
            #pragma unroll
            for (int r = 0; r < 4; ++r)
                sc[t][r] = exp2f(sc[t][r] - msub[r]);
        #pragma unroll
        for (int r = 0; r < 4; ++r)
            lrow[r] += (sc[0][r] + sc[1][r]) + (sc[2][r] + sc[3][r]);

        const short* vt = svt + g * 2048;
        #pragma unroll
        for (int hh = 0; hh < 2; ++hh) {
            #pragma unroll
            for (int tt = 0; tt < 2; ++tt) {
                int t = hh * 2 + tt;
                int gphys = (tt * 2 + (l15 >> 3)) ^ quad;
                #pragma unroll
                for (int r = 0; r < 4; ++r)
                    pw[(gphys * 17 + quad * 4 + r) * 8 + (l15 & 7)] = f2bf(sc[t][r]);
            }
            int gph_r = quad ^ (l15 >> 2);
            s16x8 pa  = *(const s16x8*)(pw + (gph_r * 17 + l15) * 8);
            int ksw = ((hh * 4 + quad) ^ (l15 & 7)) * 8;
            s16x8 vb0 = *(const s16x8*)(vt + l15 * 64 + ksw);
            s16x8 vb1 = *(const s16x8*)(vt + (16 + l15) * 64 + ksw);
            acc0 = __builtin_amdgcn_mfma_f32_16x16x32_bf16(pa, vb0, acc0, 0, 0, 0);
            acc1 = __builtin_amdgcn_mfma_f32_16x16x32_bf16(pa, vb1, acc1, 0, 0, 0);
        }
    }

    #pragma unroll
    for (int r = 0; r < 4; ++r) lrow[r] = rowsum16(lrow[r]);

    __syncthreads();
    if (l15 == 0) {
        #pragma unroll
        for (int r = 0; r < 4; ++r) {
            sm[w][quad * 4 + r] = mrow[r];
            sl[w][quad * 4 + r] = lrow[r];
        }
    }
    __syncthreads();
    float wgt[4], L4[4];
    #pragma unroll
    for (int r = 0; r < 4; ++r) {
        int qrow = quad * 4 + r;
        float mm = -INFINITY;
        #pragma unroll
        for (int gg = 0; gg < 4; ++gg) mm = fmaxf(mm, sm[qsub * 4 + gg][qrow]);
        float LL = 0.f;
        #pragma unroll
        for (int gg = 0; gg < 4; ++gg)
            LL += exp2f(sm[qsub * 4 + gg][qrow] - mm) * sl[qsub * 4 + gg][qrow];
        wgt[r] = exp2f(mrow[r] - mm);
        L4[r] = LL;
    }
    if (g == 0 && l15 == 0) {
        #pragma unroll
        for (int r = 0; r < 4; ++r) sLf[qsub * 16 + quad * 4 + r] = L4[r];
    }

    float* obuf = (float*)skf;
    for (int gg = 0; gg < 4; ++gg) {
        if (g == gg) {
            #pragma unroll
            for (int r = 0; r < 4; ++r) {
                int idx = (qsub * 16 + quad * 4 + r) * 33 + l15;
                float v0 = wgt[r] * acc0[r];
                float v1 = wgt[r] * acc1[r];
                if (gg == 0) { obuf[idx] = v0; obuf[idx + 16] = v1; }
                else         { obuf[idx] += v0; obuf[idx + 16] += v1; }
            }
        }
        __syncthreads();
    }

    for (int i = tid; i < 1024; i += 512) {
        int ql = i >> 5, d = i & 31;
        int qq = q0 + ql;
        if (qq < NQ_)
            xout[(size_t)(b * NQ_ + qq) * 256 + h * 32 + d] = obuf[ql * 33 + d] / sLf[ql];
    }
}

// ---------------------------------------------------------------------------
extern "C" void kernel_launch(void* const* d_in, const int* in_sizes, int n_in,
                              void* d_out, int out_size, void* d_ws, size_t ws_size,
                              hipStream_t stream)
{
    const float* query = (const float*)d_in[1];
    const float* ref2d = (const float*)d_in[2];
    const float* kin   = (const float*)d_in[3];
    const float* vin   = (const float*)d_in[4];
    const unsigned char* mask = (const unsigned char*)d_in[6];
    const float* W1x = (const float*)d_in[7];
    const float* b1x = (const float*)d_in[8];
    const float* W2x = (const float*)d_in[9];
    const float* W1y = (const float*)d_in[10];
    const float* b1y = (const float*)d_in[11];
    const float* W2y = (const float*)d_in[12];
    const float* Wq  = (const float*)d_in[13];
    const float* bq  = (const float*)d_in[14];
    const float* Wk  = (const float*)d_in[15];
    const float* bk  = (const float*)d_in[16];
    const float* Wv  = (const float*)d_in[17];
    const float* bv  = (const float*)d_in[18];
    const float* Wp  = (const float*)d_in[19];
    const float* bp  = (const float*)d_in[20];

    // Workspace ~18.6 MB (proven-safe footprint 27.8 MB)
    char* wsb = (char*)d_ws;
    unsigned short* qbf = (unsigned short*)(wsb);               //   983040 B
    unsigned short* kbf = (unsigned short*)(wsb +   983040);    //  4194304 B
    unsigned short* vbf = (unsigned short*)(wsb +  5177344);    //  4194304 B
    float* rxws = (float*)(wsb +  9371648);                     //  3686400 B
    float* ryws = (float*)(wsb + 13058048);                     //  3686400 B
    float* xws  = (float*)(wsb + 16744448);                     //  1843200 B
    float* out  = (float*)d_out;

    const float qscale = LOG2E / sqrtf(32.0f);   // exp2-domain softmax

    stage1_kernel<<<2085, 256, 0, stream>>>(
        query, kin, vin, Wq, Wk, Wv, bq, bk, bv, qbf, kbf, vbf, qscale,
        ref2d, W1x, b1x, W1y, b1y, W2x, W2y, rxws, ryws);
    attn_mfma_kernel<<<dim3(29, 8, B_), 512, 0, stream>>>(
        qbf, kbf, vbf, rxws, ryws, mask, xws);
    outproj_kernel<<<dim3(29, 4), 256, 0, stream>>>(xws, Wp, bp, out, 1800);
}

// Round 11
// 203.937 us; speedup vs baseline: 1.1924x; 1.0688x over previous
//
#include <hip/hip_runtime.h>
#include <hip/hip_bf16.h>
#include <cmath>

// Problem constants
#define B_ 2
#define NQ_ 900
#define N_ 4096
#define LOG2E 1.4426950408889634f

typedef __attribute__((ext_vector_type(4))) float f32x4;
typedef __attribute__((ext_vector_type(8))) short s16x8;
typedef __attribute__((ext_vector_type(8))) _Float16 f16x8;

__device__ inline short f2bf(float x) {
    union { __hip_bfloat16 b; short s; } u;
    u.b = __float2bfloat16(x);
    return u.s;
}
__device__ inline short f2h(float x) {
    _Float16 h = (_Float16)x;
    return __builtin_bit_cast(short, h);
}

// DPP rotate within 16-lane row (VALU pipe; replaces ds_bpermute shuffles)
template <int CTRL>
__device__ inline float dppf(float x) {
    int xi = __builtin_bit_cast(int, x);
    int r = __builtin_amdgcn_update_dpp(xi, xi, CTRL, 0xF, 0xF, true);
    return __builtin_bit_cast(float, r);
}
__device__ inline float rowmax16(float v) {
    v = fmaxf(v, dppf<0x121>(v));
    v = fmaxf(v, dppf<0x122>(v));
    v = fmaxf(v, dppf<0x124>(v));
    v = fmaxf(v, dppf<0x128>(v));
    return v;
}
__device__ inline float rowsum16(float v) {
    v += dppf<0x121>(v);
    v += dppf<0x122>(v);
    v += dppf<0x124>(v);
    v += dppf<0x128>(v);
    return v;
}

// ---------------------------------------------------------------------------
// Stage 1 v2 (FUSED proj + rpe3). Round-11 changes driven by 25.7% occupancy
// at 48 KB LDS (3 blocks/CU cap, measured ~2):
//  * proj: A-fragments in REGISTERS (each wave's A-rows are wave-private;
//    the 32 KB Ab LDS round-trip was pure overhead). Bb full-K 32 KB.
//  * rpe: 4 queries/block (450 blocks; W2 table build amortized 4x vs 1800),
//    W1 coefs + query-independent v hoisted to regs, sUV unpadded (reads
//    are 16-lane broadcasts - conflict-free without padding).
//  * LDS union 48 -> 40 KB => 4 blocks/CU ceiling.
//  blocks 0..284  : proj (29 q-tiles, 128 k-tiles, 128 v-tiles)
//  blocks 285..734: rpe3, 4 queries each
// ---------------------------------------------------------------------------
__global__ __launch_bounds__(256) void stage1_kernel(
    const float* __restrict__ query, const float* __restrict__ kin,
    const float* __restrict__ vin,
    const float* __restrict__ Wq, const float* __restrict__ Wk,
    const float* __restrict__ Wv,
    const float* __restrict__ bqv, const float* __restrict__ bkv,
    const float* __restrict__ bvv,
    unsigned short* __restrict__ qbf, unsigned short* __restrict__ kbf,
    unsigned short* __restrict__ vbf, float qscale,
    const float* __restrict__ ref2d,
    const float* __restrict__ W1x, const float* __restrict__ b1x,
    const float* __restrict__ W1y, const float* __restrict__ b1y,
    const float* __restrict__ W2x, const float* __restrict__ W2y,
    float* __restrict__ rpe_x, float* __restrict__ rpe_y)
{
    __shared__ uint4 smem[2560];          // 40 KB union
    const int bx = blockIdx.x;
    const int tid = threadIdx.x;
    const int w = tid >> 6, l = tid & 63, quad = l >> 4, l15 = l & 15;

    if (bx < 285) {
        // ------------------------------ proj ------------------------------
        short* Bb = (short*)smem;                    // 32 KB (full K, one n-tile)
        const int mtx = bx < 29 ? 0 : (bx < 157 ? 1 : 2);
        const int tile = bx - (mtx == 0 ? 0 : mtx == 1 ? 29 : 157);
        const int m0 = tile * 64;
        const float* X = mtx == 0 ? query : mtx == 1 ? kin : vin;
        const float* W = mtx == 0 ? Wq : mtx == 1 ? Wk : Wv;
        const float* bias = mtx == 0 ? bqv : mtx == 1 ? bkv : bvv;
        unsigned short* Y = mtx == 0 ? qbf : mtx == 1 ? kbf : vbf;
        const int M = mtx == 0 ? 1800 : 8192;
        const float alpha = mtx == 0 ? qscale : 1.0f;
        const int rows_per_b = mtx == 0 ? 900 : 4096;
        const int ROWS = mtx == 0 ? 960 : 4096;
        const int wq = tid & 3, mm = tid >> 2;

        // A-fragments in registers: row = m0 + w*16 + l15, k = kc*32+quad*8+j
        s16x8 afr[8];
        {
            const int arow = m0 + w * 16 + l15;
            const bool avalid = arow < M;
            const float* xr = X + (size_t)arow * 256;
            #pragma unroll
            for (int kc = 0; kc < 8; ++kc) {
                float4 a0 = make_float4(0.f, 0.f, 0.f, 0.f), a1 = a0;
                if (avalid) {
                    a0 = *(const float4*)(xr + kc * 32 + quad * 8);
                    a1 = *(const float4*)(xr + kc * 32 + quad * 8 + 4);
                }
                unsigned pk0 = (unsigned)(unsigned short)f2bf(a0.x) | ((unsigned)(unsigned short)f2bf(a0.y) << 16);
                unsigned pk1 = (unsigned)(unsigned short)f2bf(a0.z) | ((unsigned)(unsigned short)f2bf(a0.w) << 16);
                unsigned pk2 = (unsigned)(unsigned short)f2bf(a1.x) | ((unsigned)(unsigned short)f2bf(a1.y) << 16);
                unsigned pk3 = (unsigned)(unsigned short)f2bf(a1.z) | ((unsigned)(unsigned short)f2bf(a1.w) << 16);
                uint4 pk = make_uint4(pk0, pk1, pk2, pk3);
                afr[kc] = __builtin_bit_cast(s16x8, pk);
            }
        }

        for (int nt0 = 0; nt0 < 4; ++nt0) {
            const int n0 = nt0 * 64;
            {
                const float* wcol = W + n0 + mm;
                #pragma unroll
                for (int it = 0; it < 8; ++it) {
                    int g2 = it * 4 + wq;
                    uint4 wk4;
                    wk4.x = (unsigned)(unsigned short)f2bf(wcol[(g2 * 8 + 0) * 256])
                          | ((unsigned)(unsigned short)f2bf(wcol[(g2 * 8 + 1) * 256]) << 16);
                    wk4.y = (unsigned)(unsigned short)f2bf(wcol[(g2 * 8 + 2) * 256])
                          | ((unsigned)(unsigned short)f2bf(wcol[(g2 * 8 + 3) * 256]) << 16);
                    wk4.z = (unsigned)(unsigned short)f2bf(wcol[(g2 * 8 + 4) * 256])
                          | ((unsigned)(unsigned short)f2bf(wcol[(g2 * 8 + 5) * 256]) << 16);
                    wk4.w = (unsigned)(unsigned short)f2bf(wcol[(g2 * 8 + 6) * 256])
                          | ((unsigned)(unsigned short)f2bf(wcol[(g2 * 8 + 7) * 256]) << 16);
                    *(uint4*)(Bb + (it * 256 + mm * 4 + wq) * 8) = wk4;
                }
            }
            __syncthreads();

            f32x4 acc[4] = {{0.f,0.f,0.f,0.f},{0.f,0.f,0.f,0.f},{0.f,0.f,0.f,0.f},{0.f,0.f,0.f,0.f}};
            #pragma unroll
            for (int kc = 0; kc < 8; ++kc) {
                #pragma unroll
                for (int nt = 0; nt < 4; ++nt) {
                    s16x8 bf = *(const s16x8*)(Bb + (kc * 256 + (nt * 16 + l15) * 4 + quad) * 8);
                    acc[nt] = __builtin_amdgcn_mfma_f32_16x16x32_bf16(afr[kc], bf, acc[nt], 0, 0, 0);
                }
            }

            #pragma unroll
            for (int nt = 0; nt < 4; ++nt) {
                int n = n0 + nt * 16 + l15;
                float bs = bias[n];
                int h = n >> 5, d = n & 31;
                #pragma unroll
                for (int r = 0; r < 4; ++r) {
                    int row = m0 + w * 16 + quad * 4 + r;
                    if (row < M) {
                        int b = row / rows_per_b;
                        int pos = row - b * rows_per_b;
                        Y[((size_t)(b * 8 + h) * ROWS + pos) * 32 + d] =
                            (unsigned short)f2bf((acc[nt][r] + bs) * alpha);
                    }
                }
            }
            __syncthreads();
        }
    } else {
        // ------------------------------ rpe3 ------------------------------
        short* sw2h = (short*)smem;                  // 16 KB
        short* sw2l = (short*)smem + 8192;           // 16 KB
        float4* sUV = (float4*)(smem + 2048);        // 8 KB, unpadded
        const int bq0 = (bx - 285) * 4;              // 4 queries per block

        for (int i = tid; i < 8192; i += 256) {
            int g = i >> 3, j = i & 7;
            int kcg = g >> 6, rr = g & 63, n = rr >> 2, q4 = rr & 3;
            int k = kcg * 32 + q4 * 8 + j;
            float val = ((n < 8) ? W2x[k * 8 + n] : W2y[k * 8 + (n - 8)]) * LOG2E;
            _Float16 hi = (_Float16)val;
            sw2h[i] = __builtin_bit_cast(short, hi);
            sw2l[i] = f2h(val - (float)hi);
        }

        // hoist W1 coefficients (k0 = tid, k1 = tid+256) + query-independent v
        const int k0 = tid, k1 = tid + 256;
        const float w1x0a = W1x[k0], w1x1a = W1x[512 + k0];
        const float w1y0a = W1y[k0], w1y1a = W1y[512 + k0];
        const float bxa = b1x[k0], bya = b1y[k0];
        const float vxa = -(w1x0a + w1x1a), vya = -(w1y0a + w1y1a);
        const float w1x0b = W1x[k1], w1x1b = W1x[512 + k1];
        const float w1y0b = W1y[k1], w1y1b = W1y[512 + k1];
        const float bxb = b1x[k1], byb = b1y[k1];
        const float vxb = -(w1x0b + w1x1b), vyb = -(w1y0b + w1y1b);

        const int wrow = w;
        const int row = wrow * 16 + l15;
        const float pc = (row + 0.5f) * 16.0f;

        for (int qi = 0; qi < 4; ++qi) {
            const int bq = bq0 + qi;
            {
                const float4 bb = *(const float4*)(ref2d + (size_t)bq * 4);
                float x1 = bb.x - bb.z * 0.5f, x2 = bb.x + bb.z * 0.5f;
                float y1 = bb.y - bb.w * 0.5f, y2 = bb.y + bb.w * 0.5f;
                sUV[k0] = make_float4(fmaf(w1x0a, x1, fmaf(w1x1a, x2, bxa)), vxa,
                                      fmaf(w1y0a, y1, fmaf(w1y1a, y2, bya)), vya);
                sUV[k1] = make_float4(fmaf(w1x0b, x1, fmaf(w1x1b, x2, bxb)), vxb,
                                      fmaf(w1y0b, y1, fmaf(w1y1b, y2, byb)), vyb);
            }
            __syncthreads();

            f32x4 accx = {0.f, 0.f, 0.f, 0.f}, accy = {0.f, 0.f, 0.f, 0.f};
            for (int kc = 0; kc < 16; ++kc) {
                f16x8 axh, axl, ayh, ayl;
                #pragma unroll
                for (int i = 0; i < 8; ++i) {
                    float4 u = sUV[kc * 32 + quad * 8 + i];
                    float hx = fmaxf(fmaf(u.y, pc, u.x), 0.f);
                    float hy = fmaxf(fmaf(u.w, pc, u.z), 0.f);
                    _Float16 xh = (_Float16)hx;
                    _Float16 yh = (_Float16)hy;
                    axh[i] = xh;
                    axl[i] = (_Float16)(hx - (float)xh);
                    ayh[i] = yh;
                    ayl[i] = (_Float16)(hy - (float)yh);
                }
                f16x8 bh = *(const f16x8*)(sw2h + (kc * 64 + l15 * 4 + quad) * 8);
                f16x8 bl = *(const f16x8*)(sw2l + (kc * 64 + l15 * 4 + quad) * 8);
                accx = __builtin_amdgcn_mfma_f32_16x16x32_f16(axh, bh, accx, 0, 0, 0);
                accx = __builtin_amdgcn_mfma_f32_16x16x32_f16(axh, bl, accx, 0, 0, 0);
                accx = __builtin_amdgcn_mfma_f32_16x16x32_f16(axl, bh, accx, 0, 0, 0);
                accy = __builtin_amdgcn_mfma_f32_16x16x32_f16(ayh, bh, accy, 0, 0, 0);
                accy = __builtin_amdgcn_mfma_f32_16x16x32_f16(ayh, bl, accy, 0, 0, 0);
                accy = __builtin_amdgcn_mfma_f32_16x16x32_f16(ayl, bh, accy, 0, 0, 0);
            }

            #pragma unroll
            for (int rr = 0; rr < 4; ++rr) {
                int row_out = wrow * 16 + quad * 4 + rr;
                if (l15 < 8) rpe_x[((size_t)l15 * 1800 + bq) * 64 + row_out] = accx[rr];
                else         rpe_y[((size_t)(l15 - 8) * 1800 + bq) * 64 + row_out] = accy[rr];
            }
            __syncthreads();   // before next query overwrites sUV
        }
    }
}

// ---------------------------------------------------------------------------
// Output projection via fp16 hi/lo split MFMA (round-8 verified version).
// ---------------------------------------------------------------------------
__global__ __launch_bounds__(256) void outproj_kernel(
    const float* __restrict__ X, const float* __restrict__ W,
    const float* __restrict__ bias, float* __restrict__ Y, int M)
{
    __shared__ short Abh[4096], Abl[4096], Bbh[4096], Bbl[4096];
    const int tid = threadIdx.x;
    const int m0 = blockIdx.x * 64, n0 = blockIdx.y * 64;
    const int w = tid >> 6, l = tid & 63, quad = l >> 4, l15 = l & 15;
    const int wq = tid & 3, mm = tid >> 2;
    const bool valid = (m0 + mm) < M;
    const float* xr = X + (size_t)(m0 + mm) * 256;
    const float* wcol = W + n0 + mm;

    f32x4 acc[4] = {{0.f,0.f,0.f,0.f},{0.f,0.f,0.f,0.f},{0.f,0.f,0.f,0.f},{0.f,0.f,0.f,0.f}};

    for (int kq = 0; kq < 4; ++kq) {
        #pragma unroll
        for (int it = 0; it < 2; ++it) {
            int g2 = it * 4 + wq;
            int kbase = kq * 64 + g2 * 8;
            float av[8], bv[8];
            #pragma unroll
            for (int j = 0; j < 8; ++j) {
                av[j] = valid ? xr[kbase + j] : 0.f;
                bv[j] = wcol[(kbase + j) * 256];
            }
            uint4 ah, al, bh, bl;
            unsigned* ahp = (unsigned*)&ah; unsigned* alp = (unsigned*)&al;
            unsigned* bhp = (unsigned*)&bh; unsigned* blp = (unsigned*)&bl;
            #pragma unroll
            for (int j2 = 0; j2 < 4; ++j2) {
                _Float16 h0 = (_Float16)av[j2 * 2], h1 = (_Float16)av[j2 * 2 + 1];
                ahp[j2] = (unsigned)(unsigned short)__builtin_bit_cast(short, h0)
                        | ((unsigned)(unsigned short)__builtin_bit_cast(short, h1) << 16);
                alp[j2] = (unsigned)(unsigned short)f2h(av[j2 * 2] - (float)h0)
                        | ((unsigned)(unsigned short)f2h(av[j2 * 2 + 1] - (float)h1) << 16);
                _Float16 g0 = (_Float16)bv[j2 * 2], g1 = (_Float16)bv[j2 * 2 + 1];
                bhp[j2] = (unsigned)(unsigned short)__builtin_bit_cast(short, g0)
                        | ((unsigned)(unsigned short)__builtin_bit_cast(short, g1) << 16);
                blp[j2] = (unsigned)(unsigned short)f2h(bv[j2 * 2] - (float)g0)
                        | ((unsigned)(unsigned short)f2h(bv[j2 * 2 + 1] - (float)g1) << 16);
            }
            int gi = (it * 256 + mm * 4 + wq) * 8;
            *(uint4*)(Abh + gi) = ah;
            *(uint4*)(Abl + gi) = al;
            *(uint4*)(Bbh + gi) = bh;
            *(uint4*)(Bbl + gi) = bl;
        }
        __syncthreads();

        #pragma unroll
        for (int kc = 0; kc < 2; ++kc) {
            int ga = (kc * 256 + (w * 16 + l15) * 4 + quad) * 8;
            f16x8 ah = *(const f16x8*)(Abh + ga);
            f16x8 al = *(const f16x8*)(Abl + ga);
            #pragma unroll
            for (int nt = 0; nt < 4; ++nt) {
                int gb = (kc * 256 + (nt * 16 + l15) * 4 + quad) * 8;
                f16x8 bh = *(const f16x8*)(Bbh + gb);
                f16x8 bl = *(const f16x8*)(Bbl + gb);
                acc[nt] = __builtin_amdgcn_mfma_f32_16x16x32_f16(ah, bh, acc[nt], 0, 0, 0);
                acc[nt] = __builtin_amdgcn_mfma_f32_16x16x32_f16(ah, bl, acc[nt], 0, 0, 0);
                acc[nt] = __builtin_amdgcn_mfma_f32_16x16x32_f16(al, bh, acc[nt], 0, 0, 0);
            }
        }
        __syncthreads();
    }

    #pragma unroll
    for (int nt = 0; nt < 4; ++nt) {
        int n = n0 + nt * 16 + l15;
        float bs = bias[n];
        #pragma unroll
        for (int r = 0; r < 4; ++r) {
            int row = m0 + w * 16 + quad * 4 + r;
            if (row < M)
                Y[(size_t)row * 256 + n] = acc[nt][r] + bs;
        }
    }
}

// ---------------------------------------------------------------------------
// MFMA flash attention (round-1/8 verified config — unchanged).
// ---------------------------------------------------------------------------
__global__ __launch_bounds__(512, 4) void attn_mfma_kernel(
    const unsigned short* __restrict__ qb16, const unsigned short* __restrict__ kb16,
    const unsigned short* __restrict__ vb16,
    const float* __restrict__ rpe_x, const float* __restrict__ rpe_y,
    const unsigned char* __restrict__ mask, float* __restrict__ xout)
{
    __shared__ short skf[4 * 2048];
    __shared__ short svt[4 * 2048];
    __shared__ short spb[8 * 544];
    __shared__ float ry[32 * 65];
    __shared__ unsigned long long smaskb[64];
    __shared__ float sm[8][16], sl[8][16], sLf[32];

    const int tid = threadIdx.x;
    const int qb = blockIdx.x, h = blockIdx.y, b = blockIdx.z;
    const int q0 = qb * 32;
    const int w = tid >> 6, l = tid & 63;
    const int qsub = w >> 2, g = w & 3;
    const int quad = l >> 4, l15 = l & 15;

    const unsigned short* qg = qb16 + (size_t)(b * 8 + h) * 960 * 32;
    const unsigned short* kg = kb16 + (size_t)(b * 8 + h) * 4096 * 32;
    const unsigned short* vg = vb16 + (size_t)(b * 8 + h) * 4096 * 32;
    const float* rxh = rpe_x + ((size_t)h * 1800 + b * NQ_) * 64;
    const float* ryh = rpe_y + ((size_t)h * 1800 + b * NQ_) * 64;

    for (int i = tid; i < 2048; i += 512) {
        int qq = q0 + (i >> 6), pos = i & 63;
        float vy = 0.f;
        if (qq < NQ_)
            vy = ryh[(size_t)qq * 64 + pos];
        ry[(i >> 6) * 65 + pos] = vy;
    }
    #pragma unroll
    for (int j = 0; j < 8; ++j) {
        int c = w * 8 + j;
        unsigned long long bits = __ballot(mask[(size_t)b * N_ + c * 64 + l] != 0);
        if (l == 0) smaskb[c] = bits;
    }

    s16x8 qa = *(const s16x8*)(qg + (size_t)(q0 + qsub * 16 + l15) * 32 + quad * 8);

    f32x4 rx4[4];
    #pragma unroll
    for (int t = 0; t < 4; ++t)
        #pragma unroll
        for (int r = 0; r < 4; ++r) {
            int qq = q0 + qsub * 16 + quad * 4 + r;
            rx4[t][r] = (qq < NQ_) ? rxh[(size_t)qq * 64 + t * 16 + l15] : 0.f;
        }

    const int sg = tid >> 7, role = (tid >> 6) & 1, stl = tid & 63;
    int eoff[4];
    if (role == 0) {
        #pragma unroll
        for (int t = 0; t < 4; ++t)
            eoff[t] = (t * 16 + (stl & 15)) * 32 + (stl >> 4) * 8;
    } else {
        #pragma unroll
        for (int t = 0; t < 4; ++t)
            eoff[t] = stl * 32 + t * 8;
    }
    const unsigned short* src = role ? vg : kg;

    uint4 pf[4];
    {
        size_t cb = (size_t)(sg * 16) * 2048;
        #pragma unroll
        for (int t = 0; t < 4; ++t) pf[t] = *(const uint4*)(src + cb + eoff[t]);
    }

    float mrow[4] = {-INFINITY, -INFINITY, -INFINITY, -INFINITY};
    float lrow[4] = {0.f, 0.f, 0.f, 0.f};
    f32x4 acc0 = {0.f, 0.f, 0.f, 0.f}, acc1 = {0.f, 0.f, 0.f, 0.f};
    short* pw = spb + w * 544;

    for (int i = 0; i < 16; ++i) {
        __syncthreads();
        if (role == 0) {
            #pragma unroll
            for (int t = 0; t < 4; ++t)
                *(uint4*)(skf + sg * 2048 + (t * 64 + stl) * 8) = pf[t];
        } else {
            short* vtw = svt + sg * 2048;
            #pragma unroll
            for (int t = 0; t < 4; ++t) {
                const unsigned short* pv = (const unsigned short*)&pf[t];
                #pragma unroll
                for (int j = 0; j < 8; ++j) {
                    int d = t * 8 + j;
                    vtw[d * 64 + (((stl >> 3) ^ (d & 7)) << 3) + (stl & 7)] = (short)pv[j];
                }
            }
        }
        __syncthreads();

        {
            int inext = (i + 1 < 16) ? i + 1 : 15;
            size_t cb = (size_t)(sg * 16 + inext) * 2048;
            #pragma unroll
            for (int t = 0; t < 4; ++t) pf[t] = *(const uint4*)(src + cb + eoff[t]);
        }

        const int cgc = g * 16 + i;
        const short* kf = skf + g * 2048;

        f32x4 sc[4];
        #pragma unroll
        for (int t = 0; t < 4; ++t) {
            s16x8 kb = *(const s16x8*)(kf + (t * 64 + l) * 8);
            sc[t] = __builtin_amdgcn_mfma_f32_16x16x32_bf16(qa, kb, rx4[t], 0, 0, 0);
        }
        float ryv[4];
        #pragma unroll
        for (int r = 0; r < 4; ++r)
            ryv[r] = ry[(qsub * 16 + quad * 4 + r) * 65 + cgc];
        unsigned long long mb = smaskb[cgc];
        if (mb) {
            #pragma unroll
            for (int t = 0; t < 4; ++t) {
                float mk = ((mb >> (t * 16 + l15)) & 1ULL) ? -144.2695f : 0.f;
                #pragma unroll
                for (int r = 0; r < 4; ++r) sc[t][r] += mk;
            }
        }

        float cmr[4];
        #pragma unroll
        for (int r = 0; r < 4; ++r)
            cmr[r] = fmaxf(fmaxf(sc[0][r], sc[1][r]), fmaxf(sc[2][r], sc[3][r])) + ryv[r];

        int ok = (cmr[0] <= mrow[0] + 8.f) & (cmr[1] <= mrow[1] + 8.f)
               & (cmr[2] <= mrow[2] + 8.f) & (cmr[3] <= mrow[3] + 8.f);
        if (!__all(ok)) {
            #pragma unroll
            for (int r = 0; r < 4; ++r) {
                float cm = rowmax16(cmr[r]);
                float mnew = fmaxf(mrow[r], cm);
                float al = exp2f(mrow[r] - mnew);
                mrow[r] = mnew;
                lrow[r] *= al;
                acc0[r] *= al;
                acc1[r] *= al;
            }
        }

        float msub[4];
        #pragma unroll
        for (int r = 0; r < 4; ++r) msub[r] = mrow[r] - ryv[r];
        #pragma unroll
        for (int t = 0; t < 4; ++t)
            #pragma unroll
            for (int r = 0; r < 4; ++r)
                sc[t][r] = exp2f(sc[t][r] - msub[r]);
        #pragma unroll
        for (int r = 0; r < 4; ++r)
            lrow[r] += (sc[0][r] + sc[1][r]) + (sc[2][r] + sc[3][r]);

        const short* vt = svt + g * 2048;
        #pragma unroll
        for (int hh = 0; hh < 2; ++hh) {
            #pragma unroll
            for (int tt = 0; tt < 2; ++tt) {
                int t = hh * 2 + tt;
                int gphys = (tt * 2 + (l15 >> 3)) ^ quad;
                #pragma unroll
                for (int r = 0; r < 4; ++r)
                    pw[(gphys * 17 + quad * 4 + r) * 8 + (l15 & 7)] = f2bf(sc[t][r]);
            }
            int gph_r = quad ^ (l15 >> 2);
            s16x8 pa  = *(const s16x8*)(pw + (gph_r * 17 + l15) * 8);
            int ksw = ((hh * 4 + quad) ^ (l15 & 7)) * 8;
            s16x8 vb0 = *(const s16x8*)(vt + l15 * 64 + ksw);
            s16x8 vb1 = *(const s16x8*)(vt + (16 + l15) * 64 + ksw);
            acc0 = __builtin_amdgcn_mfma_f32_16x16x32_bf16(pa, vb0, acc0, 0, 0, 0);
            acc1 = __builtin_amdgcn_mfma_f32_16x16x32_bf16(pa, vb1, acc1, 0, 0, 0);
        }
    }

    #pragma unroll
    for (int r = 0; r < 4; ++r) lrow[r] = rowsum16(lrow[r]);

    __syncthreads();
    if (l15 == 0) {
        #pragma unroll
        for (int r = 0; r < 4; ++r) {
            sm[w][quad * 4 + r] = mrow[r];
            sl[w][quad * 4 + r] = lrow[r];
        }
    }
    __syncthreads();
    float wgt[4], L4[4];
    #pragma unroll
    for (int r = 0; r < 4; ++r) {
        int qrow = quad * 4 + r;
        float mm = -INFINITY;
        #pragma unroll
        for (int gg = 0; gg < 4; ++gg) mm = fmaxf(mm, sm[qsub * 4 + gg][qrow]);
        float LL = 0.f;
        #pragma unroll
        for (int gg = 0; gg < 4; ++gg)
            LL += exp2f(sm[qsub * 4 + gg][qrow] - mm) * sl[qsub * 4 + gg][qrow];
        wgt[r] = exp2f(mrow[r] - mm);
        L4[r] = LL;
    }
    if (g == 0 && l15 == 0) {
        #pragma unroll
        for (int r = 0; r < 4; ++r) sLf[qsub * 16 + quad * 4 + r] = L4[r];
    }

    float* obuf = (float*)skf;
    for (int gg = 0; gg < 4; ++gg) {
        if (g == gg) {
            #pragma unroll
            for (int r = 0; r < 4; ++r) {
                int idx = (qsub * 16 + quad * 4 + r) * 33 + l15;
                float v0 = wgt[r] * acc0[r];
                float v1 = wgt[r] * acc1[r];
                if (gg == 0) { obuf[idx] = v0; obuf[idx + 16] = v1; }
                else         { obuf[idx] += v0; obuf[idx + 16] += v1; }
            }
        }
        __syncthreads();
    }

    for (int i = tid; i < 1024; i += 512) {
        int ql = i >> 5, d = i & 31;
        int qq = q0 + ql;
        if (qq < NQ_)
            xout[(size_t)(b * NQ_ + qq) * 256 + h * 32 + d] = obuf[ql * 33 + d] / sLf[ql];
    }
}

// ---------------------------------------------------------------------------
extern "C" void kernel_launch(void* const* d_in, const int* in_sizes, int n_in,
                              void* d_out, int out_size, void* d_ws, size_t ws_size,
                              hipStream_t stream)
{
    const float* query = (const float*)d_in[1];
    const float* ref2d = (const float*)d_in[2];
    const float* kin   = (const float*)d_in[3];
    const float* vin   = (const float*)d_in[4];
    const unsigned char* mask = (const unsigned char*)d_in[6];
    const float* W1x = (const float*)d_in[7];
    const float* b1x = (const float*)d_in[8];
    const float* W2x = (const float*)d_in[9];
    const float* W1y = (const float*)d_in[10];
    const float* b1y = (const float*)d_in[11];
    const float* W2y = (const float*)d_in[12];
    const float* Wq  = (const float*)d_in[13];
    const float* bq  = (const float*)d_in[14];
    const float* Wk  = (const float*)d_in[15];
    const float* bk  = (const float*)d_in[16];
    const float* Wv  = (const float*)d_in[17];
    const float* bv  = (const float*)d_in[18];
    const float* Wp  = (const float*)d_in[19];
    const float* bp  = (const float*)d_in[20];

    // Workspace ~18.6 MB (proven-safe footprint 27.8 MB)
    char* wsb = (char*)d_ws;
    unsigned short* qbf = (unsigned short*)(wsb);               //   983040 B
    unsigned short* kbf = (unsigned short*)(wsb +   983040);    //  4194304 B
    unsigned short* vbf = (unsigned short*)(wsb +  5177344);    //  4194304 B
    float* rxws = (float*)(wsb +  9371648);                     //  3686400 B
    float* ryws = (float*)(wsb + 13058048);                     //  3686400 B
    float* xws  = (float*)(wsb + 16744448);                     //  1843200 B
    float* out  = (float*)d_out;

    const float qscale = LOG2E / sqrtf(32.0f);   // exp2-domain softmax

    stage1_kernel<<<735, 256, 0, stream>>>(
        query, kin, vin, Wq, Wk, Wv, bq, bk, bv, qbf, kbf, vbf, qscale,
        ref2d, W1x, b1x, W1y, b1y, W2x, W2y, rxws, ryws);
    attn_mfma_kernel<<<dim3(29, 8, B_), 512, 0, stream>>>(
        qbf, kbf, vbf, rxws, ryws, mask, xws);
    outproj_kernel<<<dim3(29, 4), 256, 0, stream>>>(xws, Wp, bp, out, 1800);
}

// Round 12
// 202.017 us; speedup vs baseline: 1.2037x; 1.0095x over previous
//
#include <hip/hip_runtime.h>
#include <hip/hip_bf16.h>
#include <cmath>

// Problem constants
#define B_ 2
#define NQ_ 900
#define N_ 4096
#define LOG2E 1.4426950408889634f

typedef __attribute__((ext_vector_type(4))) float f32x4;
typedef __attribute__((ext_vector_type(8))) short s16x8;
typedef __attribute__((ext_vector_type(8))) _Float16 f16x8;

__device__ inline short f2bf(float x) {
    union { __hip_bfloat16 b; short s; } u;
    u.b = __float2bfloat16(x);
    return u.s;
}
__device__ inline short f2h(float x) {
    _Float16 h = (_Float16)x;
    return __builtin_bit_cast(short, h);
}

// DPP rotate within 16-lane row (VALU pipe; replaces ds_bpermute shuffles)
template <int CTRL>
__device__ inline float dppf(float x) {
    int xi = __builtin_bit_cast(int, x);
    int r = __builtin_amdgcn_update_dpp(xi, xi, CTRL, 0xF, 0xF, true);
    return __builtin_bit_cast(float, r);
}
__device__ inline float rowmax16(float v) {
    v = fmaxf(v, dppf<0x121>(v));
    v = fmaxf(v, dppf<0x122>(v));
    v = fmaxf(v, dppf<0x124>(v));
    v = fmaxf(v, dppf<0x128>(v));
    return v;
}
__device__ inline float rowsum16(float v) {
    v += dppf<0x121>(v);
    v += dppf<0x122>(v);
    v += dppf<0x124>(v);
    v += dppf<0x128>(v);
    return v;
}

// ---------------------------------------------------------------------------
// Stage 1 v3 (FUSED proj + rpe3 + Wp-prep).
//  blocks 0..284  : proj, A-fragments in registers, Bb full-K 32 KB LDS
//  blocks 285..734: rpe3, 4 queries/block
//  blocks 735..750: Wp -> transposed f16 hi/lo pairs (round-9-verified
//                   transform, folded in here so it costs no extra launch);
//                   outproj then needs no W staging at all.
// ---------------------------------------------------------------------------
__global__ __launch_bounds__(256) void stage1_kernel(
    const float* __restrict__ query, const float* __restrict__ kin,
    const float* __restrict__ vin,
    const float* __restrict__ Wq, const float* __restrict__ Wk,
    const float* __restrict__ Wv, const float* __restrict__ Wp,
    const float* __restrict__ bqv, const float* __restrict__ bkv,
    const float* __restrict__ bvv,
    unsigned short* __restrict__ qbf, unsigned short* __restrict__ kbf,
    unsigned short* __restrict__ vbf, float qscale,
    const float* __restrict__ ref2d,
    const float* __restrict__ W1x, const float* __restrict__ b1x,
    const float* __restrict__ W1y, const float* __restrict__ b1y,
    const float* __restrict__ W2x, const float* __restrict__ W2y,
    float* __restrict__ rpe_x, float* __restrict__ rpe_y,
    unsigned short* __restrict__ wph, unsigned short* __restrict__ wpl)
{
    __shared__ uint4 smem[2560];          // 40 KB union
    const int bx = blockIdx.x;
    const int tid = threadIdx.x;
    const int w = tid >> 6, l = tid & 63, quad = l >> 4, l15 = l & 15;

    if (bx < 285) {
        // ------------------------------ proj ------------------------------
        short* Bb = (short*)smem;                    // 32 KB (full K, one n-tile)
        const int mtx = bx < 29 ? 0 : (bx < 157 ? 1 : 2);
        const int tile = bx - (mtx == 0 ? 0 : mtx == 1 ? 29 : 157);
        const int m0 = tile * 64;
        const float* X = mtx == 0 ? query : mtx == 1 ? kin : vin;
        const float* W = mtx == 0 ? Wq : mtx == 1 ? Wk : Wv;
        const float* bias = mtx == 0 ? bqv : mtx == 1 ? bkv : bvv;
        unsigned short* Y = mtx == 0 ? qbf : mtx == 1 ? kbf : vbf;
        const int M = mtx == 0 ? 1800 : 8192;
        const float alpha = mtx == 0 ? qscale : 1.0f;
        const int rows_per_b = mtx == 0 ? 900 : 4096;
        const int ROWS = mtx == 0 ? 960 : 4096;
        const int wq = tid & 3, mm = tid >> 2;

        // A-fragments in registers: row = m0 + w*16 + l15, k = kc*32+quad*8+j
        s16x8 afr[8];
        {
            const int arow = m0 + w * 16 + l15;
            const bool avalid = arow < M;
            const float* xr = X + (size_t)arow * 256;
            #pragma unroll
            for (int kc = 0; kc < 8; ++kc) {
                float4 a0 = make_float4(0.f, 0.f, 0.f, 0.f), a1 = a0;
                if (avalid) {
                    a0 = *(const float4*)(xr + kc * 32 + quad * 8);
                    a1 = *(const float4*)(xr + kc * 32 + quad * 8 + 4);
                }
                unsigned pk0 = (unsigned)(unsigned short)f2bf(a0.x) | ((unsigned)(unsigned short)f2bf(a0.y) << 16);
                unsigned pk1 = (unsigned)(unsigned short)f2bf(a0.z) | ((unsigned)(unsigned short)f2bf(a0.w) << 16);
                unsigned pk2 = (unsigned)(unsigned short)f2bf(a1.x) | ((unsigned)(unsigned short)f2bf(a1.y) << 16);
                unsigned pk3 = (unsigned)(unsigned short)f2bf(a1.z) | ((unsigned)(unsigned short)f2bf(a1.w) << 16);
                uint4 pk = make_uint4(pk0, pk1, pk2, pk3);
                afr[kc] = __builtin_bit_cast(s16x8, pk);
            }
        }

        for (int nt0 = 0; nt0 < 4; ++nt0) {
            const int n0 = nt0 * 64;
            {
                const float* wcol = W + n0 + mm;
                #pragma unroll
                for (int it = 0; it < 8; ++it) {
                    int g2 = it * 4 + wq;
                    uint4 wk4;
                    wk4.x = (unsigned)(unsigned short)f2bf(wcol[(g2 * 8 + 0) * 256])
                          | ((unsigned)(unsigned short)f2bf(wcol[(g2 * 8 + 1) * 256]) << 16);
                    wk4.y = (unsigned)(unsigned short)f2bf(wcol[(g2 * 8 + 2) * 256])
                          | ((unsigned)(unsigned short)f2bf(wcol[(g2 * 8 + 3) * 256]) << 16);
                    wk4.z = (unsigned)(unsigned short)f2bf(wcol[(g2 * 8 + 4) * 256])
                          | ((unsigned)(unsigned short)f2bf(wcol[(g2 * 8 + 5) * 256]) << 16);
                    wk4.w = (unsigned)(unsigned short)f2bf(wcol[(g2 * 8 + 6) * 256])
                          | ((unsigned)(unsigned short)f2bf(wcol[(g2 * 8 + 7) * 256]) << 16);
                    *(uint4*)(Bb + (it * 256 + mm * 4 + wq) * 8) = wk4;
                }
            }
            __syncthreads();

            f32x4 acc[4] = {{0.f,0.f,0.f,0.f},{0.f,0.f,0.f,0.f},{0.f,0.f,0.f,0.f},{0.f,0.f,0.f,0.f}};
            #pragma unroll
            for (int kc = 0; kc < 8; ++kc) {
                #pragma unroll
                for (int nt = 0; nt < 4; ++nt) {
                    s16x8 bf = *(const s16x8*)(Bb + (kc * 256 + (nt * 16 + l15) * 4 + quad) * 8);
                    acc[nt] = __builtin_amdgcn_mfma_f32_16x16x32_bf16(afr[kc], bf, acc[nt], 0, 0, 0);
                }
            }

            #pragma unroll
            for (int nt = 0; nt < 4; ++nt) {
                int n = n0 + nt * 16 + l15;
                float bs = bias[n];
                int h = n >> 5, d = n & 31;
                #pragma unroll
                for (int r = 0; r < 4; ++r) {
                    int row = m0 + w * 16 + quad * 4 + r;
                    if (row < M) {
                        int b = row / rows_per_b;
                        int pos = row - b * rows_per_b;
                        Y[((size_t)(b * 8 + h) * ROWS + pos) * 32 + d] =
                            (unsigned short)f2bf((acc[nt][r] + bs) * alpha);
                    }
                }
            }
            __syncthreads();
        }
    } else if (bx < 735) {
        // ------------------------------ rpe3 ------------------------------
        short* sw2h = (short*)smem;                  // 16 KB
        short* sw2l = (short*)smem + 8192;           // 16 KB
        float4* sUV = (float4*)(smem + 2048);        // 8 KB, unpadded
        const int bq0 = (bx - 285) * 4;              // 4 queries per block

        for (int i = tid; i < 8192; i += 256) {
            int g = i >> 3, j = i & 7;
            int kcg = g >> 6, rr = g & 63, n = rr >> 2, q4 = rr & 3;
            int k = kcg * 32 + q4 * 8 + j;
            float val = ((n < 8) ? W2x[k * 8 + n] : W2y[k * 8 + (n - 8)]) * LOG2E;
            _Float16 hi = (_Float16)val;
            sw2h[i] = __builtin_bit_cast(short, hi);
            sw2l[i] = f2h(val - (float)hi);
        }

        // hoist W1 coefficients (k0 = tid, k1 = tid+256) + query-independent v
        const int k0 = tid, k1 = tid + 256;
        const float w1x0a = W1x[k0], w1x1a = W1x[512 + k0];
        const float w1y0a = W1y[k0], w1y1a = W1y[512 + k0];
        const float bxa = b1x[k0], bya = b1y[k0];
        const float vxa = -(w1x0a + w1x1a), vya = -(w1y0a + w1y1a);
        const float w1x0b = W1x[k1], w1x1b = W1x[512 + k1];
        const float w1y0b = W1y[k1], w1y1b = W1y[512 + k1];
        const float bxb = b1x[k1], byb = b1y[k1];
        const float vxb = -(w1x0b + w1x1b), vyb = -(w1y0b + w1y1b);

        const int wrow = w;
        const int row = wrow * 16 + l15;
        const float pc = (row + 0.5f) * 16.0f;

        for (int qi = 0; qi < 4; ++qi) {
            const int bq = bq0 + qi;
            {
                const float4 bb = *(const float4*)(ref2d + (size_t)bq * 4);
                float x1 = bb.x - bb.z * 0.5f, x2 = bb.x + bb.z * 0.5f;
                float y1 = bb.y - bb.w * 0.5f, y2 = bb.y + bb.w * 0.5f;
                sUV[k0] = make_float4(fmaf(w1x0a, x1, fmaf(w1x1a, x2, bxa)), vxa,
                                      fmaf(w1y0a, y1, fmaf(w1y1a, y2, bya)), vya);
                sUV[k1] = make_float4(fmaf(w1x0b, x1, fmaf(w1x1b, x2, bxb)), vxb,
                                      fmaf(w1y0b, y1, fmaf(w1y1b, y2, byb)), vyb);
            }
            __syncthreads();

            f32x4 accx = {0.f, 0.f, 0.f, 0.f}, accy = {0.f, 0.f, 0.f, 0.f};
            for (int kc = 0; kc < 16; ++kc) {
                f16x8 axh, axl, ayh, ayl;
                #pragma unroll
                for (int i = 0; i < 8; ++i) {
                    float4 u = sUV[kc * 32 + quad * 8 + i];
                    float hx = fmaxf(fmaf(u.y, pc, u.x), 0.f);
                    float hy = fmaxf(fmaf(u.w, pc, u.z), 0.f);
                    _Float16 xh = (_Float16)hx;
                    _Float16 yh = (_Float16)hy;
                    axh[i] = xh;
                    axl[i] = (_Float16)(hx - (float)xh);
                    ayh[i] = yh;
                    ayl[i] = (_Float16)(hy - (float)yh);
                }
                f16x8 bh = *(const f16x8*)(sw2h + (kc * 64 + l15 * 4 + quad) * 8);
                f16x8 bl = *(const f16x8*)(sw2l + (kc * 64 + l15 * 4 + quad) * 8);
                accx = __builtin_amdgcn_mfma_f32_16x16x32_f16(axh, bh, accx, 0, 0, 0);
                accx = __builtin_amdgcn_mfma_f32_16x16x32_f16(axh, bl, accx, 0, 0, 0);
                accx = __builtin_amdgcn_mfma_f32_16x16x32_f16(axl, bh, accx, 0, 0, 0);
                accy = __builtin_amdgcn_mfma_f32_16x16x32_f16(ayh, bh, accy, 0, 0, 0);
                accy = __builtin_amdgcn_mfma_f32_16x16x32_f16(ayh, bl, accy, 0, 0, 0);
                accy = __builtin_amdgcn_mfma_f32_16x16x32_f16(ayl, bh, accy, 0, 0, 0);
            }

            #pragma unroll
            for (int rr = 0; rr < 4; ++rr) {
                int row_out = wrow * 16 + quad * 4 + rr;
                if (l15 < 8) rpe_x[((size_t)l15 * 1800 + bq) * 64 + row_out] = accx[rr];
                else         rpe_y[((size_t)(l15 - 8) * 1800 + bq) * 64 + row_out] = accy[rr];
            }
            __syncthreads();   // before next query overwrites sUV
        }
    } else {
        // --------------------- Wp -> f16 hi/lo W^T ------------------------
        // (round-9-verified transform; 16 blocks, 64x64 tile each)
        const int tile = bx - 735;                   // 0..15
        const int kt = tile >> 2, ntile = tile & 3;
        unsigned short* th = (unsigned short*)smem;  // 64*72 ushort = 9.2 KB
        unsigned short* tl = th + 64 * 72;           // 9.2 KB
        #pragma unroll
        for (int p = 0; p < 4; ++p) {
            int kl = p * 16 + (tid >> 4);
            int nl = (tid & 15) * 4;
            float4 v = *(const float4*)(Wp + (size_t)(kt * 64 + kl) * 256 + ntile * 64 + nl);
            float vv[4] = {v.x, v.y, v.z, v.w};
            #pragma unroll
            for (int i = 0; i < 4; ++i) {
                _Float16 h = (_Float16)vv[i];
                th[(nl + i) * 72 + kl] = (unsigned short)__builtin_bit_cast(short, h);
                tl[(nl + i) * 72 + kl] = (unsigned short)f2h(vv[i] - (float)h);
            }
        }
        __syncthreads();
        #pragma unroll
        for (int p = 0; p < 2; ++p) {
            int nl = p * 32 + (tid >> 3);
            int k8 = (tid & 7) * 8;
            uint4 pk;
            unsigned short* ps = (unsigned short*)&pk;
            #pragma unroll
            for (int j = 0; j < 8; ++j) ps[j] = th[nl * 72 + k8 + j];
            *(uint4*)(wph + (size_t)(ntile * 64 + nl) * 256 + kt * 64 + k8) = pk;
            #pragma unroll
            for (int j = 0; j < 8; ++j) ps[j] = tl[nl * 72 + k8 + j];
            *(uint4*)(wpl + (size_t)(ntile * 64 + nl) * 256 + kt * 64 + k8) = pk;
        }
    }
}

// ---------------------------------------------------------------------------
// Output projection v2: A-fragments (X hi/lo split) in REGISTERS (rows are
// wave-private — round-11 proj pattern), B-fragments direct from prep'd
// wph/wpl. Zero LDS, zero barriers — the k-loop is pure MFMA + global reads.
// ---------------------------------------------------------------------------
__global__ __launch_bounds__(256) void outproj_kernel(
    const float* __restrict__ X,
    const unsigned short* __restrict__ wph, const unsigned short* __restrict__ wpl,
    const float* __restrict__ bias, float* __restrict__ Y, int M)
{
    const int tid = threadIdx.x;
    const int m0 = blockIdx.x * 64, n0 = blockIdx.y * 64;
    const int w = tid >> 6, l = tid & 63, quad = l >> 4, l15 = l & 15;

    const int arow = m0 + w * 16 + l15;
    const bool avalid = arow < M;
    const float* xr = X + (size_t)arow * 256;

    f16x8 ah[8], al[8];
    #pragma unroll
    for (int kc = 0; kc < 8; ++kc) {
        float4 a0 = make_float4(0.f, 0.f, 0.f, 0.f), a1 = a0;
        if (avalid) {
            a0 = *(const float4*)(xr + kc * 32 + quad * 8);
            a1 = *(const float4*)(xr + kc * 32 + quad * 8 + 4);
        }
        float av[8] = {a0.x, a0.y, a0.z, a0.w, a1.x, a1.y, a1.z, a1.w};
        #pragma unroll
        for (int j = 0; j < 8; ++j) {
            _Float16 h = (_Float16)av[j];
            ah[kc][j] = h;
            al[kc][j] = (_Float16)(av[j] - (float)h);
        }
    }

    f32x4 acc[4] = {{0.f,0.f,0.f,0.f},{0.f,0.f,0.f,0.f},{0.f,0.f,0.f,0.f},{0.f,0.f,0.f,0.f}};
    #pragma unroll
    for (int kc = 0; kc < 8; ++kc) {
        #pragma unroll
        for (int nt = 0; nt < 4; ++nt) {
            size_t gb = (size_t)(n0 + nt * 16 + l15) * 256 + kc * 32 + quad * 8;
            f16x8 bh = *(const f16x8*)(wph + gb);
            f16x8 bl = *(const f16x8*)(wpl + gb);
            acc[nt] = __builtin_amdgcn_mfma_f32_16x16x32_f16(ah[kc], bh, acc[nt], 0, 0, 0);
            acc[nt] = __builtin_amdgcn_mfma_f32_16x16x32_f16(ah[kc], bl, acc[nt], 0, 0, 0);
            acc[nt] = __builtin_amdgcn_mfma_f32_16x16x32_f16(al[kc], bh, acc[nt], 0, 0, 0);
        }
    }

    #pragma unroll
    for (int nt = 0; nt < 4; ++nt) {
        int n = n0 + nt * 16 + l15;
        float bs = bias[n];
        #pragma unroll
        for (int r = 0; r < 4; ++r) {
            int row = m0 + w * 16 + quad * 4 + r;
            if (row < M)
                Y[(size_t)row * 256 + n] = acc[nt][r] + bs;
        }
    }
}

// ---------------------------------------------------------------------------
// MFMA flash attention (round-1/8 verified config — unchanged).
// ---------------------------------------------------------------------------
__global__ __launch_bounds__(512, 4) void attn_mfma_kernel(
    const unsigned short* __restrict__ qb16, const unsigned short* __restrict__ kb16,
    const unsigned short* __restrict__ vb16,
    const float* __restrict__ rpe_x, const float* __restrict__ rpe_y,
    const unsigned char* __restrict__ mask, float* __restrict__ xout)
{
    __shared__ short skf[4 * 2048];
    __shared__ short svt[4 * 2048];
    __shared__ short spb[8 * 544];
    __shared__ float ry[32 * 65];
    __shared__ unsigned long long smaskb[64];
    __shared__ float sm[8][16], sl[8][16], sLf[32];

    const int tid = threadIdx.x;
    const int qb = blockIdx.x, h = blockIdx.y, b = blockIdx.z;
    const int q0 = qb * 32;
    const int w = tid >> 6, l = tid & 63;
    const int qsub = w >> 2, g = w & 3;
    const int quad = l >> 4, l15 = l & 15;

    const unsigned short* qg = qb16 + (size_t)(b * 8 + h) * 960 * 32;
    const unsigned short* kg = kb16 + (size_t)(b * 8 + h) * 4096 * 32;
    const unsigned short* vg = vb16 + (size_t)(b * 8 + h) * 4096 * 32;
    const float* rxh = rpe_x + ((size_t)h * 1800 + b * NQ_) * 64;
    const float* ryh = rpe_y + ((size_t)h * 1800 + b * NQ_) * 64;

    for (int i = tid; i < 2048; i += 512) {
        int qq = q0 + (i >> 6), pos = i & 63;
        float vy = 0.f;
        if (qq < NQ_)
            vy = ryh[(size_t)qq * 64 + pos];
        ry[(i >> 6) * 65 + pos] = vy;
    }
    #pragma unroll
    for (int j = 0; j < 8; ++j) {
        int c = w * 8 + j;
        unsigned long long bits = __ballot(mask[(size_t)b * N_ + c * 64 + l] != 0);
        if (l == 0) smaskb[c] = bits;
    }

    s16x8 qa = *(const s16x8*)(qg + (size_t)(q0 + qsub * 16 + l15) * 32 + quad * 8);

    f32x4 rx4[4];
    #pragma unroll
    for (int t = 0; t < 4; ++t)
        #pragma unroll
        for (int r = 0; r < 4; ++r) {
            int qq = q0 + qsub * 16 + quad * 4 + r;
            rx4[t][r] = (qq < NQ_) ? rxh[(size_t)qq * 64 + t * 16 + l15] : 0.f;
        }

    const int sg = tid >> 7, role = (tid >> 6) & 1, stl = tid & 63;
    int eoff[4];
    if (role == 0) {
        #pragma unroll
        for (int t = 0; t < 4; ++t)
            eoff[t] = (t * 16 + (stl & 15)) * 32 + (stl >> 4) * 8;
    } else {
        #pragma unroll
        for (int t = 0; t < 4; ++t)
            eoff[t] = stl * 32 + t * 8;
    }
    const unsigned short* src = role ? vg : kg;

    uint4 pf[4];
    {
        size_t cb = (size_t)(sg * 16) * 2048;
        #pragma unroll
        for (int t = 0; t < 4; ++t) pf[t] = *(const uint4*)(src + cb + eoff[t]);
    }

    float mrow[4] = {-INFINITY, -INFINITY, -INFINITY, -INFINITY};
    float lrow[4] = {0.f, 0.f, 0.f, 0.f};
    f32x4 acc0 = {0.f, 0.f, 0.f, 0.f}, acc1 = {0.f, 0.f, 0.f, 0.f};
    short* pw = spb + w * 544;

    for (int i = 0; i < 16; ++i) {
        __syncthreads();
        if (role == 0) {
            #pragma unroll
            for (int t = 0; t < 4; ++t)
                *(uint4*)(skf + sg * 2048 + (t * 64 + stl) * 8) = pf[t];
        } else {
            short* vtw = svt + sg * 2048;
            #pragma unroll
            for (int t = 0; t < 4; ++t) {
                const unsigned short* pv = (const unsigned short*)&pf[t];
                #pragma unroll
                for (int j = 0; j < 8; ++j) {
                    int d = t * 8 + j;
                    vtw[d * 64 + (((stl >> 3) ^ (d & 7)) << 3) + (stl & 7)] = (short)pv[j];
                }
            }
        }
        __syncthreads();

        {
            int inext = (i + 1 < 16) ? i + 1 : 15;
            size_t cb = (size_t)(sg * 16 + inext) * 2048;
            #pragma unroll
            for (int t = 0; t < 4; ++t) pf[t] = *(const uint4*)(src + cb + eoff[t]);
        }

        const int cgc = g * 16 + i;
        const short* kf = skf + g * 2048;

        f32x4 sc[4];
        #pragma unroll
        for (int t = 0; t < 4; ++t) {
            s16x8 kb = *(const s16x8*)(kf + (t * 64 + l) * 8);
            sc[t] = __builtin_amdgcn_mfma_f32_16x16x32_bf16(qa, kb, rx4[t], 0, 0, 0);
        }
        float ryv[4];
        #pragma unroll
        for (int r = 0; r < 4; ++r)
            ryv[r] = ry[(qsub * 16 + quad * 4 + r) * 65 + cgc];
        unsigned long long mb = smaskb[cgc];
        if (mb) {
            #pragma unroll
            for (int t = 0; t < 4; ++t) {
                float mk = ((mb >> (t * 16 + l15)) & 1ULL) ? -144.2695f : 0.f;
                #pragma unroll
                for (int r = 0; r < 4; ++r) sc[t][r] += mk;
            }
        }

        float cmr[4];
        #pragma unroll
        for (int r = 0; r < 4; ++r)
            cmr[r] = fmaxf(fmaxf(sc[0][r], sc[1][r]), fmaxf(sc[2][r], sc[3][r])) + ryv[r];

        int ok = (cmr[0] <= mrow[0] + 8.f) & (cmr[1] <= mrow[1] + 8.f)
               & (cmr[2] <= mrow[2] + 8.f) & (cmr[3] <= mrow[3] + 8.f);
        if (!__all(ok)) {
            #pragma unroll
            for (int r = 0; r < 4; ++r) {
                float cm = rowmax16(cmr[r]);
                float mnew = fmaxf(mrow[r], cm);
                float al = exp2f(mrow[r] - mnew);
                mrow[r] = mnew;
                lrow[r] *= al;
                acc0[r] *= al;
                acc1[r] *= al;
            }
        }

        float msub[4];
        #pragma unroll
        for (int r = 0; r < 4; ++r) msub[r] = mrow[r] - ryv[r];
        #pragma unroll
        for (int t = 0; t < 4; ++t)
            #pragma unroll
            for (int r = 0; r < 4; ++r)
                sc[t][r] = exp2f(sc[t][r] - msub[r]);
        #pragma unroll
        for (int r = 0; r < 4; ++r)
            lrow[r] += (sc[0][r] + sc[1][r]) + (sc[2][r] + sc[3][r]);

        const short* vt = svt + g * 2048;
        #pragma unroll
        for (int hh = 0; hh < 2; ++hh) {
            #pragma unroll
            for (int tt = 0; tt < 2; ++tt) {
                int t = hh * 2 + tt;
                int gphys = (tt * 2 + (l15 >> 3)) ^ quad;
                #pragma unroll
                for (int r = 0; r < 4; ++r)
                    pw[(gphys * 17 + quad * 4 + r) * 8 + (l15 & 7)] = f2bf(sc[t][r]);
            }
            int gph_r = quad ^ (l15 >> 2);
            s16x8 pa  = *(const s16x8*)(pw + (gph_r * 17 + l15) * 8);
            int ksw = ((hh * 4 + quad) ^ (l15 & 7)) * 8;
            s16x8 vb0 = *(const s16x8*)(vt + l15 * 64 + ksw);
            s16x8 vb1 = *(const s16x8*)(vt + (16 + l15) * 64 + ksw);
            acc0 = __builtin_amdgcn_mfma_f32_16x16x32_bf16(pa, vb0, acc0, 0, 0, 0);
            acc1 = __builtin_amdgcn_mfma_f32_16x16x32_bf16(pa, vb1, acc1, 0, 0, 0);
        }
    }

    #pragma unroll
    for (int r = 0; r < 4; ++r) lrow[r] = rowsum16(lrow[r]);

    __syncthreads();
    if (l15 == 0) {
        #pragma unroll
        for (int r = 0; r < 4; ++r) {
            sm[w][quad * 4 + r] = mrow[r];
            sl[w][quad * 4 + r] = lrow[r];
        }
    }
    __syncthreads();
    float wgt[4], L4[4];
    #pragma unroll
    for (int r = 0; r < 4; ++r) {
        int qrow = quad * 4 + r;
        float mm = -INFINITY;
        #pragma unroll
        for (int gg = 0; gg < 4; ++gg) mm = fmaxf(mm, sm[qsub * 4 + gg][qrow]);
        float LL = 0.f;
        #pragma unroll
        for (int gg = 0; gg < 4; ++gg)
            LL += exp2f(sm[qsub * 4 + gg][qrow] - mm) * sl[qsub * 4 + gg][qrow];
        wgt[r] = exp2f(mrow[r] - mm);
        L4[r] = LL;
    }
    if (g == 0 && l15 == 0) {
        #pragma unroll
        for (int r = 0; r < 4; ++r) sLf[qsub * 16 + quad * 4 + r] = L4[r];
    }

    float* obuf = (float*)skf;
    for (int gg = 0; gg < 4; ++gg) {
        if (g == gg) {
            #pragma unroll
            for (int r = 0; r < 4; ++r) {
                int idx = (qsub * 16 + quad * 4 + r) * 33 + l15;
                float v0 = wgt[r] * acc0[r];
                float v1 = wgt[r] * acc1[r];
                if (gg == 0) { obuf[idx] = v0; obuf[idx + 16] = v1; }
                else         { obuf[idx] += v0; obuf[idx + 16] += v1; }
            }
        }
        __syncthreads();
    }

    for (int i = tid; i < 1024; i += 512) {
        int ql = i >> 5, d = i & 31;
        int qq = q0 + ql;
        if (qq < NQ_)
            xout[(size_t)(b * NQ_ + qq) * 256 + h * 32 + d] = obuf[ql * 33 + d] / sLf[ql];
    }
}

// ---------------------------------------------------------------------------
extern "C" void kernel_launch(void* const* d_in, const int* in_sizes, int n_in,
                              void* d_out, int out_size, void* d_ws, size_t ws_size,
                              hipStream_t stream)
{
    const float* query = (const float*)d_in[1];
    const float* ref2d = (const float*)d_in[2];
    const float* kin   = (const float*)d_in[3];
    const float* vin   = (const float*)d_in[4];
    const unsigned char* mask = (const unsigned char*)d_in[6];
    const float* W1x = (const float*)d_in[7];
    const float* b1x = (const float*)d_in[8];
    const float* W2x = (const float*)d_in[9];
    const float* W1y = (const float*)d_in[10];
    const float* b1y = (const float*)d_in[11];
    const float* W2y = (const float*)d_in[12];
    const float* Wq  = (const float*)d_in[13];
    const float* bq  = (const float*)d_in[14];
    const float* Wk  = (const float*)d_in[15];
    const float* bk  = (const float*)d_in[16];
    const float* Wv  = (const float*)d_in[17];
    const float* bv  = (const float*)d_in[18];
    const float* Wp  = (const float*)d_in[19];
    const float* bp  = (const float*)d_in[20];

    // Workspace ~18.9 MB (proven-safe footprint 27.8 MB)
    char* wsb = (char*)d_ws;
    unsigned short* qbf = (unsigned short*)(wsb);               //   983040 B
    unsigned short* kbf = (unsigned short*)(wsb +   983040);    //  4194304 B
    unsigned short* vbf = (unsigned short*)(wsb +  5177344);    //  4194304 B
    float* rxws = (float*)(wsb +  9371648);                     //  3686400 B
    float* ryws = (float*)(wsb + 13058048);                     //  3686400 B
    float* xws  = (float*)(wsb + 16744448);                     //  1843200 B
    unsigned short* wph = (unsigned short*)(wsb + 18587648);    //   131072 B
    unsigned short* wpl = (unsigned short*)(wsb + 18718720);    //   131072 B
    float* out  = (float*)d_out;

    const float qscale = LOG2E / sqrtf(32.0f);   // exp2-domain softmax

    stage1_kernel<<<751, 256, 0, stream>>>(
        query, kin, vin, Wq, Wk, Wv, Wp, bq, bk, bv, qbf, kbf, vbf, qscale,
        ref2d, W1x, b1x, W1y, b1y, W2x, W2y, rxws, ryws, wph, wpl);
    attn_mfma_kernel<<<dim3(29, 8, B_), 512, 0, stream>>>(
        qbf, kbf, vbf, rxws, ryws, mask, xws);
    outproj_kernel<<<dim3(29, 4), 256, 0, stream>>>(
        xws, wph, wpl, bp, out, 1800);
}